// Round 2
// baseline (878.413 us; speedup 1.0000x reference)
//
#include <hip/hip_runtime.h>

#define T_LEN 512
#define B_SZ  64

__device__ __forceinline__ float sigf(float x) {
    return 1.0f / (1.0f + __expf(-x));
}
__device__ __forceinline__ float tanhf_(float x) {
    return 2.0f / (1.0f + __expf(-2.0f * x)) - 1.0f;
}
// Broadcast lane `lane`'s value of v to all lanes (v_readlane -> SGPR).
__device__ __forceinline__ float readlane_f(float v, int lane) {
    return __int_as_float(__builtin_amdgcn_readlane(__float_as_int(v), lane));
}

// ---------------- GEMM1: Z1 = gather(emb, tok) @ Wx1 + b1 ----------------
// Z1 layout: (T*B, 512), row r = t*64 + b, cols [fwd 256 | bwd 256]
__global__ __launch_bounds__(256) void gemm1_kernel(
    const int* __restrict__ tok, const float* __restrict__ emb,
    const float* __restrict__ w1f, const float* __restrict__ b1f,
    const float* __restrict__ w1b, const float* __restrict__ b1b,
    float* __restrict__ Z1)
{
    const int row0  = blockIdx.x * 64;
    const int dir   = blockIdx.y >> 2;
    const int nbase = (blockIdx.y & 3) * 64;
    const float* __restrict__ W    = dir ? w1b : w1f;
    const float* __restrict__ bias = dir ? b1b : b1f;

    __shared__ float As[64][20];
    __shared__ float Bs[20][64];
    __shared__ int   toks[64];

    const int tid = threadIdx.x;
    if (tid < 64) {
        int r = row0 + tid;
        int b = r & 63, t = r >> 6;
        toks[tid] = tok[b * T_LEN + t];
    }
    __syncthreads();

    float acc[4][4] = {};
    const int ty = tid >> 4, tx = tid & 15;

    for (int k0 = 0; k0 < 300; k0 += 20) {
        #pragma unroll
        for (int q = 0; q < 5; ++q) {
            int idx = tid + q * 256;
            int mm = idx / 20, kk = idx - mm * 20;
            As[mm][kk] = emb[(size_t)toks[mm] * 300 + (k0 + kk)];
            int kk2 = idx >> 6, nn = idx & 63;
            Bs[kk2][nn] = W[(k0 + kk2) * 256 + nbase + nn];
        }
        __syncthreads();
        #pragma unroll
        for (int kk = 0; kk < 20; ++kk) {
            float4 bv = *(const float4*)&Bs[kk][tx * 4];
            #pragma unroll
            for (int i = 0; i < 4; ++i) {
                float a = As[ty * 4 + i][kk];
                acc[i][0] = fmaf(a, bv.x, acc[i][0]);
                acc[i][1] = fmaf(a, bv.y, acc[i][1]);
                acc[i][2] = fmaf(a, bv.z, acc[i][2]);
                acc[i][3] = fmaf(a, bv.w, acc[i][3]);
            }
        }
        __syncthreads();
    }

    const float4 bvad = *(const float4*)&bias[nbase + tx * 4];
    #pragma unroll
    for (int i = 0; i < 4; ++i) {
        float4 o;
        o.x = acc[i][0] + bvad.x;
        o.y = acc[i][1] + bvad.y;
        o.z = acc[i][2] + bvad.z;
        o.w = acc[i][3] + bvad.w;
        *(float4*)&Z1[(size_t)(row0 + ty * 4 + i) * 512 + dir * 256 + nbase + tx * 4] = o;
    }
}

// ---------------- GEMM2: Z2 = H1 @ Wx2 + b2 ----------------
// H1: (T*B, 128) cols [fwd 64 | bwd 64]; Z2: (T*B, 256) cols [fwd 128 | bwd 128]
__global__ __launch_bounds__(256) void gemm2_kernel(
    const float* __restrict__ H1,
    const float* __restrict__ w2f, const float* __restrict__ b2f,
    const float* __restrict__ w2b, const float* __restrict__ b2b,
    float* __restrict__ Z2)
{
    const int row0  = blockIdx.x * 64;
    const int dir   = blockIdx.y >> 1;
    const int nbase = (blockIdx.y & 1) * 64;
    const float* __restrict__ W    = dir ? w2b : w2f;
    const float* __restrict__ bias = dir ? b2b : b2f;

    __shared__ float As[64][17];   // +1 pad: breaks bank conflict at stride 16
    __shared__ float Bs[16][64];

    const int tid = threadIdx.x;
    const int ty = tid >> 4, tx = tid & 15;
    float acc[4][4] = {};

    for (int k0 = 0; k0 < 128; k0 += 16) {
        #pragma unroll
        for (int q = 0; q < 4; ++q) {
            int idx = tid + q * 256;
            int mm = idx >> 4, kk = idx & 15;
            As[mm][kk] = H1[(size_t)(row0 + mm) * 128 + k0 + kk];
            int kk2 = idx >> 6, nn = idx & 63;
            Bs[kk2][nn] = W[(k0 + kk2) * 128 + nbase + nn];
        }
        __syncthreads();
        #pragma unroll
        for (int kk = 0; kk < 16; ++kk) {
            float4 bv = *(const float4*)&Bs[kk][tx * 4];
            #pragma unroll
            for (int i = 0; i < 4; ++i) {
                float a = As[ty * 4 + i][kk];
                acc[i][0] = fmaf(a, bv.x, acc[i][0]);
                acc[i][1] = fmaf(a, bv.y, acc[i][1]);
                acc[i][2] = fmaf(a, bv.z, acc[i][2]);
                acc[i][3] = fmaf(a, bv.w, acc[i][3]);
            }
        }
        __syncthreads();
    }

    const float4 bvad = *(const float4*)&bias[nbase + tx * 4];
    #pragma unroll
    for (int i = 0; i < 4; ++i) {
        float4 o;
        o.x = acc[i][0] + bvad.x;
        o.y = acc[i][1] + bvad.y;
        o.z = acc[i][2] + bvad.z;
        o.w = acc[i][3] + bvad.w;
        *(float4*)&Z2[(size_t)(row0 + ty * 4 + i) * 256 + dir * 128 + nbase + tx * 4] = o;
    }
}

// ---------------- LSTM layer 1: one block per (batch, dir), 4 waves ----------------
// Thread j owns gate column j. Every thread redundantly updates (c,h) for unit
// u=j&63, so each 64-lane wave holds the whole h-vector one-unit-per-lane and
// the next matvec broadcasts h via v_readlane — no LDS h exchange. One barrier
// per step (double-buffered gate LDS).
__global__ __launch_bounds__(256) void lstm1_kernel(
    const float* __restrict__ Z1,
    const float* __restrict__ w1f, const float* __restrict__ w1b,
    float* __restrict__ H1)
{
    const int b   = blockIdx.x & 63;
    const int dir = blockIdx.x >> 6;
    const int j   = threadIdx.x;            // 0..255 (column)
    const int u   = j & 63;                 // unit
    const int gate = j >> 6;                // 0:f 1:i 2:g 3:o
    const float* __restrict__ W = dir ? w1b : w1f;

    float wcol[64];                         // Wh column j in VGPRs
    #pragma unroll
    for (int v = 0; v < 64; ++v)
        wcol[v] = W[(300 + v) * 256 + j];

    __shared__ float g_lds[2][256];

    float c = 0.0f;
    float h = 0.0f;                          // h for unit u (all lanes valid)

    const float* __restrict__ zcol = Z1 + dir * 256 + j;
    const int t0 = dir ? (T_LEN - 1) : 0;
    float z_cur = zcol[(size_t)(t0 * 64 + b) * 512];

    for (int s = 0; s < T_LEN; ++s) {
        const int t  = dir ? (T_LEN - 1 - s) : s;
        const int s2 = (s + 1 < T_LEN) ? (s + 1) : s;
        const int t2 = dir ? (T_LEN - 1 - s2) : s2;
        float z_next = zcol[(size_t)(t2 * 64 + b) * 512];   // prefetch

        // a_j = sum_v h_v * Wh[v][j], h_v broadcast from lane v of this wave
        float a0 = 0.f, a1 = 0.f, a2 = 0.f, a3 = 0.f;
        #pragma unroll
        for (int q = 0; q < 16; ++q) {
            a0 = fmaf(readlane_f(h, 4 * q + 0), wcol[4 * q + 0], a0);
            a1 = fmaf(readlane_f(h, 4 * q + 1), wcol[4 * q + 1], a1);
            a2 = fmaf(readlane_f(h, 4 * q + 2), wcol[4 * q + 2], a2);
            a3 = fmaf(readlane_f(h, 4 * q + 3), wcol[4 * q + 3], a3);
        }
        float zz = z_cur + ((a0 + a1) + (a2 + a3));
        float act = (gate == 2) ? tanhf_(zz) : sigf(zz);

        const int p = s & 1;
        g_lds[p][j] = act;
        __syncthreads();                     // the only barrier per step
        float f  = g_lds[p][u];
        float ii = g_lds[p][64 + u];
        float gg = g_lds[p][128 + u];
        float oo = g_lds[p][192 + u];
        c = fmaf(f, c, ii * gg);
        h = oo * tanhf_(c);
        if (j < 64)
            H1[(size_t)(t * 64 + b) * 128 + dir * 64 + u] = h;
        z_cur = z_next;
    }
}

// ---------------- LSTM layer 2: one block per (batch, dir), ONE wave, 0 barriers --
// Lane l owns cols l and l+64 of the 128 gate columns. u=l&31, p=l>>5.
//   col l    : p=0 -> f_u (sig),  p=1 -> i_u (sig)
//   col l+64 : p=0 -> g_u (tanh), p=1 -> o_u (sig)
// Gate exchange is one __shfl_xor(32) pair; (c,h) updated redundantly in both
// half-waves; h broadcast via v_readlane. Fully wave-synchronous.
__global__ __launch_bounds__(64) void lstm2_kernel(
    const float* __restrict__ Z2,
    const float* __restrict__ w2f, const float* __restrict__ w2b,
    float* __restrict__ H2)
{
    const int b   = blockIdx.x & 63;
    const int dir = blockIdx.x >> 6;
    const int l   = threadIdx.x;            // 0..63
    const int u   = l & 31;
    const int p   = l >> 5;
    const float* __restrict__ W = dir ? w2b : w2f;

    float wcol0[32], wcol1[32];
    #pragma unroll
    for (int v = 0; v < 32; ++v) {
        wcol0[v] = W[(128 + v) * 128 + l];
        wcol1[v] = W[(128 + v) * 128 + l + 64];
    }

    float c = 0.0f, h = 0.0f;

    const float* __restrict__ zbase = Z2 + dir * 128;
    const int t0 = dir ? (T_LEN - 1) : 0;
    float z0 = zbase[(size_t)(t0 * 64 + b) * 256 + l];
    float z1 = zbase[(size_t)(t0 * 64 + b) * 256 + l + 64];

    // branchless tanh/sigmoid selector for column 1
    const float km  = p ? -1.0f : -2.0f;
    const float num = p ?  1.0f :  2.0f;
    const float off = p ?  0.0f :  1.0f;

    for (int s = 0; s < T_LEN; ++s) {
        const int s2 = (s + 1 < T_LEN) ? (s + 1) : s;
        const int t2 = dir ? (T_LEN - 1 - s2) : s2;
        float zn0 = zbase[(size_t)(t2 * 64 + b) * 256 + l];
        float zn1 = zbase[(size_t)(t2 * 64 + b) * 256 + l + 64];

        float acc0 = 0.f, acc1 = 0.f;
        #pragma unroll
        for (int v = 0; v < 32; ++v) {
            float hv = readlane_f(h, v);
            acc0 = fmaf(hv, wcol0[v], acc0);
            acc1 = fmaf(hv, wcol1[v], acc1);
        }
        float zz0 = z0 + acc0;
        float zz1 = z1 + acc1;
        float a0 = sigf(zz0);                          // f or i (both sigmoid)
        float e  = __expf(km * zz1);
        float a1 = num / (1.0f + e) - off;             // tanh (p=0) or sigmoid (p=1)

        float x0 = __shfl_xor(a0, 32);
        float x1 = __shfl_xor(a1, 32);
        float f  = (p == 0) ? a0 : x0;
        float ii = (p == 0) ? x0 : a0;
        float gg = (p == 0) ? a1 : x1;
        float oo = (p == 0) ? x1 : a1;
        c = fmaf(f, c, ii * gg);
        h = oo * tanhf_(c);

        z0 = zn0; z1 = zn1;
    }
    if (p == 0)
        H2[b * 64 + dir * 32 + u] = h;
}

// ---------------- Dense head: relu(h2 @ wd + bd) @ wo + bo -> sigmoid ----------------
__global__ __launch_bounds__(256) void head_kernel(
    const float* __restrict__ H2,
    const float* __restrict__ wd, const float* __restrict__ bd,
    const float* __restrict__ wo, const float* __restrict__ bo,
    float* __restrict__ out)
{
    const int tid = threadIdx.x;
    const int b = tid >> 2, qd = tid & 3;    // 4 threads per batch row

    float hv[64];
    #pragma unroll
    for (int u = 0; u < 64; ++u) hv[u] = H2[b * 64 + u];

    float part = 0.0f;
    #pragma unroll
    for (int iq = 0; iq < 8; ++iq) {
        int i = qd * 8 + iq;
        float a = bd[i];
        #pragma unroll
        for (int u = 0; u < 64; ++u)
            a = fmaf(hv[u], wd[u * 32 + i], a);
        a = fmaxf(a, 0.0f);
        part = fmaf(a, wo[i], part);
    }

    __shared__ float ps[256];
    ps[tid] = part;
    __syncthreads();
    if (qd == 0) {
        float s = ps[tid] + ps[tid + 1] + ps[tid + 2] + ps[tid + 3];
        out[b] = sigf(s + bo[0]);
    }
}

extern "C" void kernel_launch(void* const* d_in, const int* in_sizes, int n_in,
                              void* d_out, int out_size, void* d_ws, size_t ws_size,
                              hipStream_t stream)
{
    const int*   tok = (const int*)  d_in[0];
    const float* emb = (const float*)d_in[1];
    const float* w1f = (const float*)d_in[2];
    const float* b1f = (const float*)d_in[3];
    const float* w1b = (const float*)d_in[4];
    const float* b1b = (const float*)d_in[5];
    const float* w2f = (const float*)d_in[6];
    const float* b2f = (const float*)d_in[7];
    const float* w2b = (const float*)d_in[8];
    const float* b2b = (const float*)d_in[9];
    const float* wd  = (const float*)d_in[10];
    const float* bd  = (const float*)d_in[11];
    const float* wo  = (const float*)d_in[12];
    const float* bo  = (const float*)d_in[13];
    float* out = (float*)d_out;

    // Workspace layout (fp32):
    //   Z1: 32768 x 512  (67.1 MB); H1: 32768 x 128 (16.8 MB); H2: 64 x 64
    //   Z2 aliases Z1 (Z1 dead after lstm1)
    float* Z1 = (float*)d_ws;
    float* H1 = Z1 + (size_t)32768 * 512;
    float* H2 = H1 + (size_t)32768 * 128;
    float* Z2 = Z1;

    gemm1_kernel<<<dim3(512, 8), 256, 0, stream>>>(tok, emb, w1f, b1f, w1b, b1b, Z1);
    lstm1_kernel<<<128, 256, 0, stream>>>(Z1, w1f, w1b, H1);
    gemm2_kernel<<<dim3(512, 4), 256, 0, stream>>>(H1, w2f, b2f, w2b, b2b, Z2);
    lstm2_kernel<<<128, 64, 0, stream>>>(Z2, w2f, w2b, H2);
    head_kernel<<<1, 256, 0, stream>>>(H2, wd, bd, wo, bo, out);
}

// Round 3
// 676.713 us; speedup vs baseline: 1.2981x; 1.2981x over previous
//
#include <hip/hip_runtime.h>

#define T_LEN 512
#define B_SZ  64

__device__ __forceinline__ float sigf(float x) {
    return 1.0f / (1.0f + __expf(-x));
}
__device__ __forceinline__ float tanhf_(float x) {
    return 2.0f / (1.0f + __expf(-2.0f * x)) - 1.0f;
}

// ---------------- GEMM1: Z1 = gather(emb, tok) @ Wx1 + b1 ----------------
// Z1 layout: [dir*64+b][t][256]  (chain-contiguous for lstm1 streaming)
// Block: 64 rows = one b, 64 consecutive t.  grid.x: b*8 + tchunk, grid.y: dir*4+nchunk
__global__ __launch_bounds__(256) void gemm1_kernel(
    const int* __restrict__ tok, const float* __restrict__ emb,
    const float* __restrict__ w1f, const float* __restrict__ b1f,
    const float* __restrict__ w1b, const float* __restrict__ b1b,
    float* __restrict__ Z1)
{
    const int b     = blockIdx.x >> 3;
    const int t0    = (blockIdx.x & 7) * 64;
    const int dir   = blockIdx.y >> 2;
    const int nbase = (blockIdx.y & 3) * 64;
    const float* __restrict__ W    = dir ? w1b : w1f;
    const float* __restrict__ bias = dir ? b1b : b1f;

    __shared__ float As[64][20];
    __shared__ float Bs[20][64];
    __shared__ int   toks[64];

    const int tid = threadIdx.x;
    if (tid < 64) toks[tid] = tok[b * T_LEN + t0 + tid];
    __syncthreads();

    float acc[4][4] = {};
    const int ty = tid >> 4, tx = tid & 15;

    for (int k0 = 0; k0 < 300; k0 += 20) {
        #pragma unroll
        for (int q = 0; q < 5; ++q) {
            int idx = tid + q * 256;
            int mm = idx / 20, kk = idx - mm * 20;
            As[mm][kk] = emb[(size_t)toks[mm] * 300 + (k0 + kk)];
            int kk2 = idx >> 6, nn = idx & 63;
            Bs[kk2][nn] = W[(k0 + kk2) * 256 + nbase + nn];
        }
        __syncthreads();
        #pragma unroll
        for (int kk = 0; kk < 20; ++kk) {
            float4 bv = *(const float4*)&Bs[kk][tx * 4];
            #pragma unroll
            for (int i = 0; i < 4; ++i) {
                float a = As[ty * 4 + i][kk];
                acc[i][0] = fmaf(a, bv.x, acc[i][0]);
                acc[i][1] = fmaf(a, bv.y, acc[i][1]);
                acc[i][2] = fmaf(a, bv.z, acc[i][2]);
                acc[i][3] = fmaf(a, bv.w, acc[i][3]);
            }
        }
        __syncthreads();
    }

    const float4 bvad = *(const float4*)&bias[nbase + tx * 4];
    const size_t rbase = (size_t)dir * 32768 + (size_t)b * 512 + t0;
    #pragma unroll
    for (int i = 0; i < 4; ++i) {
        float4 o;
        o.x = acc[i][0] + bvad.x;
        o.y = acc[i][1] + bvad.y;
        o.z = acc[i][2] + bvad.z;
        o.w = acc[i][3] + bvad.w;
        *(float4*)&Z1[(rbase + ty * 4 + i) * 256 + nbase + tx * 4] = o;
    }
}

// ---------------- GEMM2: Z2 = H1 @ Wx2 + b2 ----------------
// H1 layout: [b][t][128] (cols fwd64|bwd64).  Z2 layout: [dir*64+b][t][128]
__global__ __launch_bounds__(256) void gemm2_kernel(
    const float* __restrict__ H1,
    const float* __restrict__ w2f, const float* __restrict__ b2f,
    const float* __restrict__ w2b, const float* __restrict__ b2b,
    float* __restrict__ Z2)
{
    const int row0  = blockIdx.x * 64;          // rows r = b*512 + t
    const int dir   = blockIdx.y >> 1;
    const int nbase = (blockIdx.y & 1) * 64;
    const float* __restrict__ W    = dir ? w2b : w2f;
    const float* __restrict__ bias = dir ? b2b : b2f;

    __shared__ float As[64][17];   // +1 pad
    __shared__ float Bs[16][64];

    const int tid = threadIdx.x;
    const int ty = tid >> 4, tx = tid & 15;
    float acc[4][4] = {};

    for (int k0 = 0; k0 < 128; k0 += 16) {
        #pragma unroll
        for (int q = 0; q < 4; ++q) {
            int idx = tid + q * 256;
            int mm = idx >> 4, kk = idx & 15;
            As[mm][kk] = H1[(size_t)(row0 + mm) * 128 + k0 + kk];
            int kk2 = idx >> 6, nn = idx & 63;
            Bs[kk2][nn] = W[(k0 + kk2) * 128 + nbase + nn];
        }
        __syncthreads();
        #pragma unroll
        for (int kk = 0; kk < 16; ++kk) {
            float4 bv = *(const float4*)&Bs[kk][tx * 4];
            #pragma unroll
            for (int i = 0; i < 4; ++i) {
                float a = As[ty * 4 + i][kk];
                acc[i][0] = fmaf(a, bv.x, acc[i][0]);
                acc[i][1] = fmaf(a, bv.y, acc[i][1]);
                acc[i][2] = fmaf(a, bv.z, acc[i][2]);
                acc[i][3] = fmaf(a, bv.w, acc[i][3]);
            }
        }
        __syncthreads();
    }

    const float4 bvad = *(const float4*)&bias[nbase + tx * 4];
    const size_t rbase = (size_t)dir * 32768 + row0;
    #pragma unroll
    for (int i = 0; i < 4; ++i) {
        float4 o;
        o.x = acc[i][0] + bvad.x;
        o.y = acc[i][1] + bvad.y;
        o.z = acc[i][2] + bvad.z;
        o.w = acc[i][3] + bvad.w;
        *(float4*)&Z2[(rbase + ty * 4 + i) * 128 + nbase + tx * 4] = o;
    }
}

// ---------------- LSTM layer 1: one block per b, BOTH dirs (8 waves) ----------------
// dir = tid>>8, col j = tid&255, unit u = j&63. Matvec reads wave-private h copy
// in LDS via float4 broadcast. All threads redundantly update (c,h) for unit u,
// each wave writes its own h copy (same-wave RAW, no barrier). Gate exchange:
// double-buffered LDS, ONE barrier/step. Z prefetched 4 steps deep (contiguous).
__global__ __launch_bounds__(512) void lstm1_kernel(
    const float* __restrict__ Z1,
    const float* __restrict__ w1f, const float* __restrict__ w1b,
    float* __restrict__ H1)
{
    const int b    = blockIdx.x;
    const int tid  = threadIdx.x;
    const int dir  = tid >> 8;
    const int j    = tid & 255;
    const int u    = j & 63;
    const int gate = j >> 6;
    const int pw   = tid >> 6;       // physical wave 0..7
    const int lwave= pw & 3;         // wave within its dir group
    const float* __restrict__ W = dir ? w1b : w1f;

    float wcol[64];
    #pragma unroll
    for (int v = 0; v < 64; ++v)
        wcol[v] = W[(300 + v) * 256 + j];

    __shared__ float g_lds[2][2][256];                 // [parity][dir][col]
    __shared__ __align__(16) float h_own[8][64];       // per-wave h copy

    float c = 0.0f, h = 0.0f;
    h_own[pw][u] = 0.0f;             // own-wave init, no barrier needed

    const float* __restrict__ zptr =
        Z1 + ((size_t)dir * 32768 + (size_t)b * 512) * 256 + j;

    float zc[4], zn[4];
    #pragma unroll
    for (int q = 0; q < 4; ++q) {
        int t = dir ? (T_LEN - 1 - q) : q;
        zc[q] = zptr[(size_t)t * 256];
    }

    for (int s0 = 0; s0 < T_LEN; s0 += 4) {
        #pragma unroll
        for (int q = 0; q < 4; ++q) {
            int sp = s0 + 4 + q; if (sp > T_LEN - 1) sp = T_LEN - 1;
            int t = dir ? (T_LEN - 1 - sp) : sp;
            zn[q] = zptr[(size_t)t * 256];
        }
        #pragma unroll
        for (int q = 0; q < 4; ++q) {
            const float4* h4 = (const float4*)h_own[pw];
            float a0 = 0.f, a1 = 0.f, a2 = 0.f, a3 = 0.f;
            #pragma unroll
            for (int r = 0; r < 16; ++r) {
                float4 hv = h4[r];
                a0 = fmaf(hv.x, wcol[4 * r + 0], a0);
                a1 = fmaf(hv.y, wcol[4 * r + 1], a1);
                a2 = fmaf(hv.z, wcol[4 * r + 2], a2);
                a3 = fmaf(hv.w, wcol[4 * r + 3], a3);
            }
            float zz = zc[q] + ((a0 + a1) + (a2 + a3));
            float act = (gate == 2) ? tanhf_(zz) : sigf(zz);
            g_lds[q & 1][dir][j] = act;
            __syncthreads();                       // the only barrier per step
            float f  = g_lds[q & 1][dir][u];
            float ii = g_lds[q & 1][dir][64 + u];
            float gg = g_lds[q & 1][dir][128 + u];
            float oo = g_lds[q & 1][dir][192 + u];
            c = fmaf(f, c, ii * gg);
            h = oo * tanhf_(c);
            h_own[pw][u] = h;
            if (lwave == 0) {
                int t = dir ? (T_LEN - 1 - (s0 + q)) : (s0 + q);
                H1[((size_t)b * 512 + t) * 128 + dir * 64 + u] = h;
            }
        }
        #pragma unroll
        for (int q = 0; q < 4; ++q) zc[q] = zn[q];
    }
}

// ---------------- LSTM layer 2: one wave per (b,dir), ZERO barriers ----------------
// Lane l owns cols l and l+64. u=l&31, p=l>>5. h kept in wave-private LDS (32
// floats), matvec via 8 float4 broadcasts. Gate exchange: one __shfl_xor(32)
// pair. Z prefetched 4 steps deep (contiguous layout).
__global__ __launch_bounds__(64) void lstm2_kernel(
    const float* __restrict__ Z2,
    const float* __restrict__ w2f, const float* __restrict__ w2b,
    float* __restrict__ H2)
{
    const int b   = blockIdx.x & 63;
    const int dir = blockIdx.x >> 6;
    const int l   = threadIdx.x;
    const int u   = l & 31;
    const int p   = l >> 5;
    const float* __restrict__ W = dir ? w2b : w2f;

    float wcol0[32], wcol1[32];
    #pragma unroll
    for (int v = 0; v < 32; ++v) {
        wcol0[v] = W[(128 + v) * 128 + l];
        wcol1[v] = W[(128 + v) * 128 + l + 64];
    }

    __shared__ __align__(16) float h_lds[32];
    float c = 0.0f, h = 0.0f;
    if (p == 0) h_lds[u] = 0.0f;     // same-wave RAW, no barrier

    const float* __restrict__ zb =
        Z2 + ((size_t)dir * 32768 + (size_t)b * 512) * 128;

    // branchless tanh/sigmoid selector for column 1
    const float km  = p ? -1.0f : -2.0f;
    const float num = p ?  1.0f :  2.0f;
    const float off = p ?  0.0f :  1.0f;

    float zc0[4], zc1[4], zn0[4], zn1[4];
    #pragma unroll
    for (int q = 0; q < 4; ++q) {
        int t = dir ? (T_LEN - 1 - q) : q;
        zc0[q] = zb[(size_t)t * 128 + l];
        zc1[q] = zb[(size_t)t * 128 + 64 + l];
    }

    for (int s0 = 0; s0 < T_LEN; s0 += 4) {
        #pragma unroll
        for (int q = 0; q < 4; ++q) {
            int sp = s0 + 4 + q; if (sp > T_LEN - 1) sp = T_LEN - 1;
            int t = dir ? (T_LEN - 1 - sp) : sp;
            zn0[q] = zb[(size_t)t * 128 + l];
            zn1[q] = zb[(size_t)t * 128 + 64 + l];
        }
        #pragma unroll
        for (int q = 0; q < 4; ++q) {
            const float4* h4 = (const float4*)h_lds;
            float acc0 = 0.f, acc1 = 0.f;
            #pragma unroll
            for (int r = 0; r < 8; ++r) {
                float4 hv = h4[r];
                acc0 = fmaf(hv.x, wcol0[4 * r + 0], acc0);
                acc0 = fmaf(hv.y, wcol0[4 * r + 1], acc0);
                acc0 = fmaf(hv.z, wcol0[4 * r + 2], acc0);
                acc0 = fmaf(hv.w, wcol0[4 * r + 3], acc0);
                acc1 = fmaf(hv.x, wcol1[4 * r + 0], acc1);
                acc1 = fmaf(hv.y, wcol1[4 * r + 1], acc1);
                acc1 = fmaf(hv.z, wcol1[4 * r + 2], acc1);
                acc1 = fmaf(hv.w, wcol1[4 * r + 3], acc1);
            }
            float zz0 = zc0[q] + acc0;
            float zz1 = zc1[q] + acc1;
            float a0 = sigf(zz0);                  // f (p=0) or i (p=1)
            float e  = __expf(km * zz1);
            float a1 = num / (1.0f + e) - off;     // g=tanh (p=0) or o=sig (p=1)

            float x0 = __shfl_xor(a0, 32);
            float x1 = __shfl_xor(a1, 32);
            float f  = (p == 0) ? a0 : x0;
            float ii = (p == 0) ? x0 : a0;
            float gg = (p == 0) ? a1 : x1;
            float oo = (p == 0) ? x1 : a1;
            c = fmaf(f, c, ii * gg);
            h = oo * tanhf_(c);
            if (p == 0) h_lds[u] = h;              // same-wave RAW
        }
        #pragma unroll
        for (int q = 0; q < 4; ++q) { zc0[q] = zn0[q]; zc1[q] = zn1[q]; }
    }
    if (p == 0)
        H2[b * 64 + dir * 32 + u] = h;
}

// ---------------- Dense head: relu(h2 @ wd + bd) @ wo + bo -> sigmoid ----------------
__global__ __launch_bounds__(256) void head_kernel(
    const float* __restrict__ H2,
    const float* __restrict__ wd, const float* __restrict__ bd,
    const float* __restrict__ wo, const float* __restrict__ bo,
    float* __restrict__ out)
{
    const int tid = threadIdx.x;
    const int b = tid >> 2, qd = tid & 3;

    float hv[64];
    #pragma unroll
    for (int v = 0; v < 64; ++v) hv[v] = H2[b * 64 + v];

    float part = 0.0f;
    #pragma unroll
    for (int iq = 0; iq < 8; ++iq) {
        int i = qd * 8 + iq;
        float a = bd[i];
        #pragma unroll
        for (int v = 0; v < 64; ++v)
            a = fmaf(hv[v], wd[v * 32 + i], a);
        a = fmaxf(a, 0.0f);
        part = fmaf(a, wo[i], part);
    }

    __shared__ float ps[256];
    ps[tid] = part;
    __syncthreads();
    if (qd == 0) {
        float s = ps[tid] + ps[tid + 1] + ps[tid + 2] + ps[tid + 3];
        out[b] = sigf(s + bo[0]);
    }
}

extern "C" void kernel_launch(void* const* d_in, const int* in_sizes, int n_in,
                              void* d_out, int out_size, void* d_ws, size_t ws_size,
                              hipStream_t stream)
{
    const int*   tok = (const int*)  d_in[0];
    const float* emb = (const float*)d_in[1];
    const float* w1f = (const float*)d_in[2];
    const float* b1f = (const float*)d_in[3];
    const float* w1b = (const float*)d_in[4];
    const float* b1b = (const float*)d_in[5];
    const float* w2f = (const float*)d_in[6];
    const float* b2f = (const float*)d_in[7];
    const float* w2b = (const float*)d_in[8];
    const float* b2b = (const float*)d_in[9];
    const float* wd  = (const float*)d_in[10];
    const float* bd  = (const float*)d_in[11];
    const float* wo  = (const float*)d_in[12];
    const float* bo  = (const float*)d_in[13];
    float* out = (float*)d_out;

    // Workspace (fp32):
    //   Z1: [2*64][512][256] = 16.78M floats (67.1 MB)
    //   H1: [64][512][128]   =  4.19M floats (16.8 MB)
    //   H2: 64x64
    //   Z2 aliases Z1 (dead after lstm1): [2*64][512][128]
    float* Z1 = (float*)d_ws;
    float* H1 = Z1 + (size_t)2 * 64 * 512 * 256;
    float* H2 = H1 + (size_t)64 * 512 * 128;
    float* Z2 = Z1;

    gemm1_kernel<<<dim3(512, 8), 256, 0, stream>>>(tok, emb, w1f, b1f, w1b, b1b, Z1);
    lstm1_kernel<<<64, 512, 0, stream>>>(Z1, w1f, w1b, H1);
    gemm2_kernel<<<dim3(512, 4), 256, 0, stream>>>(H1, w2f, b2f, w2b, b2b, Z2);
    lstm2_kernel<<<128, 64, 0, stream>>>(Z2, w2f, w2b, H2);
    head_kernel<<<1, 256, 0, stream>>>(H2, wd, bd, wo, bo, out);
}

// Round 4
// 667.607 us; speedup vs baseline: 1.3158x; 1.0136x over previous
//
#include <hip/hip_runtime.h>

#define T_LEN 512
#define B_SZ  64

typedef _Float16 h2_t __attribute__((ext_vector_type(2)));

#if defined(__has_builtin)
#  if __has_builtin(__builtin_amdgcn_fdot2)
#    define FDOT2(a, b, c) __builtin_amdgcn_fdot2((a), (b), (c), false)
#  endif
#endif
#ifndef FDOT2
__device__ __forceinline__ float fdot2_fb(h2_t a, h2_t b, float c) {
    return fmaf((float)a[0], (float)b[0], fmaf((float)a[1], (float)b[1], c));
}
#  define FDOT2(a, b, c) fdot2_fb((a), (b), (c))
#endif

__device__ __forceinline__ float sigf(float x) {
    return 1.0f / (1.0f + __expf(-x));
}
__device__ __forceinline__ float tanhf_(float x) {
    return 2.0f / (1.0f + __expf(-2.0f * x)) - 1.0f;
}

// ---------------- GEMM1: Z1 = gather(emb, tok) @ Wx1 + b1 ----------------
// Z1 layout: [dir*64+b][t][ u*4 + g ]  (lane-local float4 per unit in lstm1)
__global__ __launch_bounds__(256) void gemm1_kernel(
    const int* __restrict__ tok, const float* __restrict__ emb,
    const float* __restrict__ w1f, const float* __restrict__ b1f,
    const float* __restrict__ w1b, const float* __restrict__ b1b,
    float* __restrict__ Z1)
{
    const int b     = blockIdx.x >> 3;
    const int t0    = (blockIdx.x & 7) * 64;
    const int dir   = blockIdx.y >> 2;
    const int nbase = (blockIdx.y & 3) * 64;   // gate g = nbase>>6 (fixed per block)
    const float* __restrict__ W    = dir ? w1b : w1f;
    const float* __restrict__ bias = dir ? b1b : b1f;

    __shared__ float As[64][20];
    __shared__ float Bs[20][64];
    __shared__ int   toks[64];

    const int tid = threadIdx.x;
    if (tid < 64) toks[tid] = tok[b * T_LEN + t0 + tid];
    __syncthreads();

    float acc[4][4] = {};
    const int ty = tid >> 4, tx = tid & 15;

    for (int k0 = 0; k0 < 300; k0 += 20) {
        #pragma unroll
        for (int q = 0; q < 5; ++q) {
            int idx = tid + q * 256;
            int mm = idx / 20, kk = idx - mm * 20;
            As[mm][kk] = emb[(size_t)toks[mm] * 300 + (k0 + kk)];
            int kk2 = idx >> 6, nn = idx & 63;
            Bs[kk2][nn] = W[(k0 + kk2) * 256 + nbase + nn];
        }
        __syncthreads();
        #pragma unroll
        for (int kk = 0; kk < 20; ++kk) {
            float4 bv = *(const float4*)&Bs[kk][tx * 4];
            #pragma unroll
            for (int i = 0; i < 4; ++i) {
                float a = As[ty * 4 + i][kk];
                acc[i][0] = fmaf(a, bv.x, acc[i][0]);
                acc[i][1] = fmaf(a, bv.y, acc[i][1]);
                acc[i][2] = fmaf(a, bv.z, acc[i][2]);
                acc[i][3] = fmaf(a, bv.w, acc[i][3]);
            }
        }
        __syncthreads();
    }

    const float4 bvad = *(const float4*)&bias[nbase + tx * 4];
    const float bb[4] = {bvad.x, bvad.y, bvad.z, bvad.w};
    const int g = nbase >> 6;
    const size_t rbase = (size_t)dir * 32768 + (size_t)b * 512 + t0;
    #pragma unroll
    for (int i = 0; i < 4; ++i) {
        float* zrow = &Z1[(rbase + ty * 4 + i) * 256];
        #pragma unroll
        for (int c = 0; c < 4; ++c) {
            int u = tx * 4 + c;
            zrow[u * 4 + g] = acc[i][c] + bb[c];
        }
    }
}

// ---------------- GEMM2: Z2 = H1 @ Wx2 + b2 ----------------
// H1: [b][t][128] (fwd64|bwd64).  Z2: [dir*64+b][t][ u*4 + g ], u<32
__global__ __launch_bounds__(256) void gemm2_kernel(
    const float* __restrict__ H1,
    const float* __restrict__ w2f, const float* __restrict__ b2f,
    const float* __restrict__ w2b, const float* __restrict__ b2b,
    float* __restrict__ Z2)
{
    const int row0  = blockIdx.x * 64;          // rows r = b*512 + t
    const int dir   = blockIdx.y >> 1;
    const int nbase = (blockIdx.y & 1) * 64;
    const float* __restrict__ W    = dir ? w2b : w2f;
    const float* __restrict__ bias = dir ? b2b : b2f;

    __shared__ float As[64][17];   // +1 pad
    __shared__ float Bs[16][64];

    const int tid = threadIdx.x;
    const int ty = tid >> 4, tx = tid & 15;
    float acc[4][4] = {};

    for (int k0 = 0; k0 < 128; k0 += 16) {
        #pragma unroll
        for (int q = 0; q < 4; ++q) {
            int idx = tid + q * 256;
            int mm = idx >> 4, kk = idx & 15;
            As[mm][kk] = H1[(size_t)(row0 + mm) * 128 + k0 + kk];
            int kk2 = idx >> 6, nn = idx & 63;
            Bs[kk2][nn] = W[(k0 + kk2) * 128 + nbase + nn];
        }
        __syncthreads();
        #pragma unroll
        for (int kk = 0; kk < 16; ++kk) {
            float4 bv = *(const float4*)&Bs[kk][tx * 4];
            #pragma unroll
            for (int i = 0; i < 4; ++i) {
                float a = As[ty * 4 + i][kk];
                acc[i][0] = fmaf(a, bv.x, acc[i][0]);
                acc[i][1] = fmaf(a, bv.y, acc[i][1]);
                acc[i][2] = fmaf(a, bv.z, acc[i][2]);
                acc[i][3] = fmaf(a, bv.w, acc[i][3]);
            }
        }
        __syncthreads();
    }

    const float4 bvad = *(const float4*)&bias[nbase + tx * 4];
    const float bb[4] = {bvad.x, bvad.y, bvad.z, bvad.w};
    const size_t rbase = (size_t)dir * 32768 + row0;
    #pragma unroll
    for (int i = 0; i < 4; ++i) {
        float* zrow = &Z2[(rbase + ty * 4 + i) * 128];
        #pragma unroll
        for (int c = 0; c < 4; ++c) {
            int n = nbase + tx * 4 + c;
            int u = n & 31, g = n >> 5;
            zrow[u * 4 + g] = acc[i][c] + bb[c];
        }
    }
}

// ---------------- LSTM layer 1: unit-per-lane, ZERO barriers ----------------
// Block = one b, 128 threads = 2 waves (wave == dir). Lane u owns unit u:
// computes f,i,g,o itself (cols u,64+u,128+u,192+u). h broadcast via
// wave-private f16 LDS row (8 uint4 broadcast reads). Matvec = 128 v_dot2.
__global__ __launch_bounds__(128) void lstm1_kernel(
    const float* __restrict__ Z1,
    const float* __restrict__ w1f, const float* __restrict__ w1b,
    float* __restrict__ H1)
{
    const int b   = blockIdx.x;
    const int tid = threadIdx.x;
    const int dir = tid >> 6;
    const int u   = tid & 63;
    const float* __restrict__ W = dir ? w1b : w1f;

    // Wh columns for the 4 gates of unit u, packed as f16 pairs over v.
    h2_t w2[4][32];
    #pragma unroll
    for (int g = 0; g < 4; ++g)
        #pragma unroll
        for (int r = 0; r < 32; ++r) {
            float wa = W[(300 + 2 * r) * 256 + g * 64 + u];
            float wb = W[(301 + 2 * r) * 256 + g * 64 + u];
            h2_t p; p[0] = (_Float16)wa; p[1] = (_Float16)wb;
            w2[g][r] = p;
        }

    __shared__ __align__(16) _Float16 h16[2][64];
    h16[dir][u] = (_Float16)0.0f;            // own-wave init, no barrier

    float c = 0.0f;

    const float* __restrict__ zrow =
        Z1 + ((size_t)(dir * 64 + b) * 512) * 256 + u * 4;

    float4 zc[4], zn[4];
    #pragma unroll
    for (int q = 0; q < 4; ++q) {
        int t = dir ? (T_LEN - 1 - q) : q;
        zc[q] = *(const float4*)&zrow[(size_t)t * 256];
    }

    float* __restrict__ hout = H1 + (size_t)b * 512 * 128 + dir * 64 + u;
    const uint4* __restrict__ hb = (const uint4*)h16[dir];

    for (int s0 = 0; s0 < T_LEN; s0 += 4) {
        #pragma unroll
        for (int q = 0; q < 4; ++q) {
            int sp = s0 + 4 + q; if (sp > T_LEN - 1) sp = T_LEN - 1;
            int t = dir ? (T_LEN - 1 - sp) : sp;
            zn[q] = *(const float4*)&zrow[(size_t)t * 256];
        }
        #pragma unroll
        for (int q = 0; q < 4; ++q) {
            float a0 = zc[q].x, a1 = zc[q].y, a2 = zc[q].z, a3 = zc[q].w;
            #pragma unroll
            for (int k = 0; k < 8; ++k) {
                uint4 hq = hb[k];
                h2_t p0 = __builtin_bit_cast(h2_t, hq.x);
                h2_t p1 = __builtin_bit_cast(h2_t, hq.y);
                h2_t p2 = __builtin_bit_cast(h2_t, hq.z);
                h2_t p3 = __builtin_bit_cast(h2_t, hq.w);
                a0 = FDOT2(p0, w2[0][4 * k + 0], a0);
                a1 = FDOT2(p0, w2[1][4 * k + 0], a1);
                a2 = FDOT2(p0, w2[2][4 * k + 0], a2);
                a3 = FDOT2(p0, w2[3][4 * k + 0], a3);
                a0 = FDOT2(p1, w2[0][4 * k + 1], a0);
                a1 = FDOT2(p1, w2[1][4 * k + 1], a1);
                a2 = FDOT2(p1, w2[2][4 * k + 1], a2);
                a3 = FDOT2(p1, w2[3][4 * k + 1], a3);
                a0 = FDOT2(p2, w2[0][4 * k + 2], a0);
                a1 = FDOT2(p2, w2[1][4 * k + 2], a1);
                a2 = FDOT2(p2, w2[2][4 * k + 2], a2);
                a3 = FDOT2(p2, w2[3][4 * k + 2], a3);
                a0 = FDOT2(p3, w2[0][4 * k + 3], a0);
                a1 = FDOT2(p3, w2[1][4 * k + 3], a1);
                a2 = FDOT2(p3, w2[2][4 * k + 3], a2);
                a3 = FDOT2(p3, w2[3][4 * k + 3], a3);
            }
            float f  = sigf(a0);
            float ii = sigf(a1);
            float gg = tanhf_(a2);
            float oo = sigf(a3);
            c = fmaf(f, c, ii * gg);
            float h = oo * tanhf_(c);

            int t = dir ? (T_LEN - 1 - (s0 + q)) : (s0 + q);
            hout[(size_t)t * 128] = h;
            h16[dir][u] = (_Float16)h;       // same-wave RAW, no barrier
        }
        #pragma unroll
        for (int q = 0; q < 4; ++q) zc[q] = zn[q];
    }
}

// ---------------- LSTM layer 2: unit-per-lane, both dirs in ONE wave ----------------
// Block = one b, 64 threads: lanes 0-31 fwd units, 32-63 bwd units.
__global__ __launch_bounds__(64) void lstm2_kernel(
    const float* __restrict__ Z2,
    const float* __restrict__ w2f, const float* __restrict__ w2b,
    float* __restrict__ H2)
{
    const int b   = blockIdx.x;
    const int l   = threadIdx.x;
    const int dir = l >> 5;
    const int u   = l & 31;
    const float* __restrict__ W = dir ? w2b : w2f;

    h2_t w2[4][16];
    #pragma unroll
    for (int g = 0; g < 4; ++g)
        #pragma unroll
        for (int r = 0; r < 16; ++r) {
            float wa = W[(128 + 2 * r) * 128 + g * 32 + u];
            float wb = W[(129 + 2 * r) * 128 + g * 32 + u];
            h2_t p; p[0] = (_Float16)wa; p[1] = (_Float16)wb;
            w2[g][r] = p;
        }

    __shared__ __align__(16) _Float16 h16[2][32];
    h16[dir][u] = (_Float16)0.0f;            // same-wave, all 64 entries covered

    float c = 0.0f, h = 0.0f;

    const float* __restrict__ zrow =
        Z2 + ((size_t)(dir * 64 + b) * 512) * 128 + u * 4;
    const uint4* __restrict__ hb = (const uint4*)h16[dir];

    float4 zc[4], zn[4];
    #pragma unroll
    for (int q = 0; q < 4; ++q) {
        int t = dir ? (T_LEN - 1 - q) : q;
        zc[q] = *(const float4*)&zrow[(size_t)t * 128];
    }

    for (int s0 = 0; s0 < T_LEN; s0 += 4) {
        #pragma unroll
        for (int q = 0; q < 4; ++q) {
            int sp = s0 + 4 + q; if (sp > T_LEN - 1) sp = T_LEN - 1;
            int t = dir ? (T_LEN - 1 - sp) : sp;
            zn[q] = *(const float4*)&zrow[(size_t)t * 128];
        }
        #pragma unroll
        for (int q = 0; q < 4; ++q) {
            float a0 = zc[q].x, a1 = zc[q].y, a2 = zc[q].z, a3 = zc[q].w;
            #pragma unroll
            for (int k = 0; k < 4; ++k) {
                uint4 hq = hb[k];
                h2_t p0 = __builtin_bit_cast(h2_t, hq.x);
                h2_t p1 = __builtin_bit_cast(h2_t, hq.y);
                h2_t p2 = __builtin_bit_cast(h2_t, hq.z);
                h2_t p3 = __builtin_bit_cast(h2_t, hq.w);
                a0 = FDOT2(p0, w2[0][4 * k + 0], a0);
                a1 = FDOT2(p0, w2[1][4 * k + 0], a1);
                a2 = FDOT2(p0, w2[2][4 * k + 0], a2);
                a3 = FDOT2(p0, w2[3][4 * k + 0], a3);
                a0 = FDOT2(p1, w2[0][4 * k + 1], a0);
                a1 = FDOT2(p1, w2[1][4 * k + 1], a1);
                a2 = FDOT2(p1, w2[2][4 * k + 1], a2);
                a3 = FDOT2(p1, w2[3][4 * k + 1], a3);
                a0 = FDOT2(p2, w2[0][4 * k + 2], a0);
                a1 = FDOT2(p2, w2[1][4 * k + 2], a1);
                a2 = FDOT2(p2, w2[2][4 * k + 2], a2);
                a3 = FDOT2(p2, w2[3][4 * k + 2], a3);
                a0 = FDOT2(p3, w2[0][4 * k + 3], a0);
                a1 = FDOT2(p3, w2[1][4 * k + 3], a1);
                a2 = FDOT2(p3, w2[2][4 * k + 3], a2);
                a3 = FDOT2(p3, w2[3][4 * k + 3], a3);
            }
            float f  = sigf(a0);
            float ii = sigf(a1);
            float gg = tanhf_(a2);
            float oo = sigf(a3);
            c = fmaf(f, c, ii * gg);
            h = oo * tanhf_(c);
            h16[dir][u] = (_Float16)h;       // same-wave RAW
        }
        #pragma unroll
        for (int q = 0; q < 4; ++q) { zc[q] = zn[q]; }
    }
    H2[b * 64 + dir * 32 + u] = h;
}

// ---------------- Dense head ----------------
__global__ __launch_bounds__(256) void head_kernel(
    const float* __restrict__ H2,
    const float* __restrict__ wd, const float* __restrict__ bd,
    const float* __restrict__ wo, const float* __restrict__ bo,
    float* __restrict__ out)
{
    const int tid = threadIdx.x;
    const int b = tid >> 2, qd = tid & 3;

    float hv[64];
    #pragma unroll
    for (int v = 0; v < 64; ++v) hv[v] = H2[b * 64 + v];

    float part = 0.0f;
    #pragma unroll
    for (int iq = 0; iq < 8; ++iq) {
        int i = qd * 8 + iq;
        float a = bd[i];
        #pragma unroll
        for (int v = 0; v < 64; ++v)
            a = fmaf(hv[v], wd[v * 32 + i], a);
        a = fmaxf(a, 0.0f);
        part = fmaf(a, wo[i], part);
    }

    __shared__ float ps[256];
    ps[tid] = part;
    __syncthreads();
    if (qd == 0) {
        float s = ps[tid] + ps[tid + 1] + ps[tid + 2] + ps[tid + 3];
        out[b] = sigf(s + bo[0]);
    }
}

extern "C" void kernel_launch(void* const* d_in, const int* in_sizes, int n_in,
                              void* d_out, int out_size, void* d_ws, size_t ws_size,
                              hipStream_t stream)
{
    const int*   tok = (const int*)  d_in[0];
    const float* emb = (const float*)d_in[1];
    const float* w1f = (const float*)d_in[2];
    const float* b1f = (const float*)d_in[3];
    const float* w1b = (const float*)d_in[4];
    const float* b1b = (const float*)d_in[5];
    const float* w2f = (const float*)d_in[6];
    const float* b2f = (const float*)d_in[7];
    const float* w2b = (const float*)d_in[8];
    const float* b2b = (const float*)d_in[9];
    const float* wd  = (const float*)d_in[10];
    const float* bd  = (const float*)d_in[11];
    const float* wo  = (const float*)d_in[12];
    const float* bo  = (const float*)d_in[13];
    float* out = (float*)d_out;

    // Workspace (fp32):
    //   Z1: [2*64][512][256] (67.1 MB); H1: [64][512][128] (16.8 MB); H2: 64x64
    //   Z2 aliases Z1 (dead after lstm1): [2*64][512][128]
    float* Z1 = (float*)d_ws;
    float* H1 = Z1 + (size_t)2 * 64 * 512 * 256;
    float* H2 = H1 + (size_t)64 * 512 * 128;
    float* Z2 = Z1;

    gemm1_kernel<<<dim3(512, 8), 256, 0, stream>>>(tok, emb, w1f, b1f, w1b, b1b, Z1);
    lstm1_kernel<<<64, 128, 0, stream>>>(Z1, w1f, w1b, H1);
    gemm2_kernel<<<dim3(512, 4), 256, 0, stream>>>(H1, w2f, b2f, w2b, b2b, Z2);
    lstm2_kernel<<<64, 64, 0, stream>>>(Z2, w2f, w2b, H2);
    head_kernel<<<1, 256, 0, stream>>>(H2, wd, bd, wo, bo, out);
}

// Round 5
// 657.535 us; speedup vs baseline: 1.3359x; 1.0153x over previous
//
#include <hip/hip_runtime.h>

#define T_LEN 512
#define B_SZ  64

typedef _Float16 h2_t __attribute__((ext_vector_type(2)));

#if defined(__has_builtin)
#  if __has_builtin(__builtin_amdgcn_fdot2)
#    define FDOT2(a, b, c) __builtin_amdgcn_fdot2((a), (b), (c), false)
#  endif
#endif
#ifndef FDOT2
__device__ __forceinline__ float fdot2_fb(h2_t a, h2_t b, float c) {
    return fmaf((float)a[0], (float)b[0], fmaf((float)a[1], (float)b[1], c));
}
#  define FDOT2(a, b, c) fdot2_fb((a), (b), (c))
#endif

__device__ __forceinline__ float sigf(float x) {
    return 1.0f / (1.0f + __expf(-x));
}
__device__ __forceinline__ float tanhf_(float x) {
    return 2.0f / (1.0f + __expf(-2.0f * x)) - 1.0f;
}

// ---------------- GEMM1: Z1 = gather(emb, tok) @ Wx1 + b1 ----------------
// Z1 layout: [dir*64+b][t][ u*4 + g ]  (lane-local float4 per unit in lstm1)
__global__ __launch_bounds__(256) void gemm1_kernel(
    const int* __restrict__ tok, const float* __restrict__ emb,
    const float* __restrict__ w1f, const float* __restrict__ b1f,
    const float* __restrict__ w1b, const float* __restrict__ b1b,
    float* __restrict__ Z1)
{
    const int b     = blockIdx.x >> 3;
    const int t0    = (blockIdx.x & 7) * 64;
    const int dir   = blockIdx.y >> 2;
    const int nbase = (blockIdx.y & 3) * 64;   // gate g = nbase>>6 (fixed per block)
    const float* __restrict__ W    = dir ? w1b : w1f;
    const float* __restrict__ bias = dir ? b1b : b1f;

    __shared__ float As[64][20];
    __shared__ float Bs[20][64];
    __shared__ int   toks[64];

    const int tid = threadIdx.x;
    if (tid < 64) toks[tid] = tok[b * T_LEN + t0 + tid];
    __syncthreads();

    float acc[4][4] = {};
    const int ty = tid >> 4, tx = tid & 15;

    for (int k0 = 0; k0 < 300; k0 += 20) {
        #pragma unroll
        for (int q = 0; q < 5; ++q) {
            int idx = tid + q * 256;
            int mm = idx / 20, kk = idx - mm * 20;
            As[mm][kk] = emb[(size_t)toks[mm] * 300 + (k0 + kk)];
            int kk2 = idx >> 6, nn = idx & 63;
            Bs[kk2][nn] = W[(k0 + kk2) * 256 + nbase + nn];
        }
        __syncthreads();
        #pragma unroll
        for (int kk = 0; kk < 20; ++kk) {
            float4 bv = *(const float4*)&Bs[kk][tx * 4];
            #pragma unroll
            for (int i = 0; i < 4; ++i) {
                float a = As[ty * 4 + i][kk];
                acc[i][0] = fmaf(a, bv.x, acc[i][0]);
                acc[i][1] = fmaf(a, bv.y, acc[i][1]);
                acc[i][2] = fmaf(a, bv.z, acc[i][2]);
                acc[i][3] = fmaf(a, bv.w, acc[i][3]);
            }
        }
        __syncthreads();
    }

    const float4 bvad = *(const float4*)&bias[nbase + tx * 4];
    const float bb[4] = {bvad.x, bvad.y, bvad.z, bvad.w};
    const int g = nbase >> 6;
    const size_t rbase = (size_t)dir * 32768 + (size_t)b * 512 + t0;
    #pragma unroll
    for (int i = 0; i < 4; ++i) {
        float* zrow = &Z1[(rbase + ty * 4 + i) * 256];
        #pragma unroll
        for (int c = 0; c < 4; ++c) {
            int u = tx * 4 + c;
            zrow[u * 4 + g] = acc[i][c] + bb[c];
        }
    }
}

// ---------------- GEMM2: Z2 = H1 @ Wx2 + b2 ----------------
// H1: [b][t][128] (fwd64|bwd64).  Z2: [dir*64+b][t][ u*4 + g ], u<32
__global__ __launch_bounds__(256) void gemm2_kernel(
    const float* __restrict__ H1,
    const float* __restrict__ w2f, const float* __restrict__ b2f,
    const float* __restrict__ w2b, const float* __restrict__ b2b,
    float* __restrict__ Z2)
{
    const int row0  = blockIdx.x * 64;          // rows r = b*512 + t
    const int dir   = blockIdx.y >> 1;
    const int nbase = (blockIdx.y & 1) * 64;
    const float* __restrict__ W    = dir ? w2b : w2f;
    const float* __restrict__ bias = dir ? b2b : b2f;

    __shared__ float As[64][17];   // +1 pad
    __shared__ float Bs[16][64];

    const int tid = threadIdx.x;
    const int ty = tid >> 4, tx = tid & 15;
    float acc[4][4] = {};

    for (int k0 = 0; k0 < 128; k0 += 16) {
        #pragma unroll
        for (int q = 0; q < 4; ++q) {
            int idx = tid + q * 256;
            int mm = idx >> 4, kk = idx & 15;
            As[mm][kk] = H1[(size_t)(row0 + mm) * 128 + k0 + kk];
            int kk2 = idx >> 6, nn = idx & 63;
            Bs[kk2][nn] = W[(k0 + kk2) * 128 + nbase + nn];
        }
        __syncthreads();
        #pragma unroll
        for (int kk = 0; kk < 16; ++kk) {
            float4 bv = *(const float4*)&Bs[kk][tx * 4];
            #pragma unroll
            for (int i = 0; i < 4; ++i) {
                float a = As[ty * 4 + i][kk];
                acc[i][0] = fmaf(a, bv.x, acc[i][0]);
                acc[i][1] = fmaf(a, bv.y, acc[i][1]);
                acc[i][2] = fmaf(a, bv.z, acc[i][2]);
                acc[i][3] = fmaf(a, bv.w, acc[i][3]);
            }
        }
        __syncthreads();
    }

    const float4 bvad = *(const float4*)&bias[nbase + tx * 4];
    const float bb[4] = {bvad.x, bvad.y, bvad.z, bvad.w};
    const size_t rbase = (size_t)dir * 32768 + row0;
    #pragma unroll
    for (int i = 0; i < 4; ++i) {
        float* zrow = &Z2[(rbase + ty * 4 + i) * 128];
        #pragma unroll
        for (int c = 0; c < 4; ++c) {
            int n = nbase + tx * 4 + c;
            int u = n & 31, g = n >> 5;
            zrow[u * 4 + g] = acc[i][c] + bb[c];
        }
    }
}

// ---------------- LSTM layer 1: unit-per-lane, ONE WAVE per (b,dir) ----------------
// Lane u owns unit u: computes f,i,g,o itself (cols u,64+u,128+u,192+u).
// h broadcast via wave-private f16 LDS row (8 uint4 broadcast reads).
// Matvec = 128 v_dot2. Zero barriers. __launch_bounds__(64,1): allow full
// VGPR budget — w2[4][32] (128 regs) must NOT spill (R4: spill at VGPR=116
// cost ~2x).
__global__ __launch_bounds__(64, 1) void lstm1_kernel(
    const float* __restrict__ Z1,
    const float* __restrict__ w1f, const float* __restrict__ w1b,
    float* __restrict__ H1)
{
    const int b   = blockIdx.x & 63;
    const int dir = blockIdx.x >> 6;
    const int u   = threadIdx.x;             // 0..63
    const float* __restrict__ W = dir ? w1b : w1f;

    // Wh columns for the 4 gates of unit u, packed as f16 pairs over v.
    h2_t w2[4][32];
    #pragma unroll
    for (int g = 0; g < 4; ++g)
        #pragma unroll
        for (int r = 0; r < 32; ++r) {
            float wa = W[(300 + 2 * r) * 256 + g * 64 + u];
            float wb = W[(301 + 2 * r) * 256 + g * 64 + u];
            h2_t p; p[0] = (_Float16)wa; p[1] = (_Float16)wb;
            w2[g][r] = p;
        }

    __shared__ __align__(16) _Float16 h16[64];
    h16[u] = (_Float16)0.0f;                 // own-wave init, no barrier

    float c = 0.0f;

    const float* __restrict__ zrow =
        Z1 + ((size_t)(dir * 64 + b) * 512) * 256 + u * 4;

    float4 zc[4], zn[4];
    #pragma unroll
    for (int q = 0; q < 4; ++q) {
        int t = dir ? (T_LEN - 1 - q) : q;
        zc[q] = *(const float4*)&zrow[(size_t)t * 256];
    }

    float* __restrict__ hout = H1 + (size_t)b * 512 * 128 + dir * 64 + u;
    const uint4* __restrict__ hb = (const uint4*)h16;

    for (int s0 = 0; s0 < T_LEN; s0 += 4) {
        #pragma unroll
        for (int q = 0; q < 4; ++q) {
            int sp = s0 + 4 + q; if (sp > T_LEN - 1) sp = T_LEN - 1;
            int t = dir ? (T_LEN - 1 - sp) : sp;
            zn[q] = *(const float4*)&zrow[(size_t)t * 256];
        }
        #pragma unroll
        for (int q = 0; q < 4; ++q) {
            float a0 = zc[q].x, a1 = zc[q].y, a2 = zc[q].z, a3 = zc[q].w;
            #pragma unroll
            for (int k = 0; k < 8; ++k) {
                uint4 hq = hb[k];
                h2_t p0 = __builtin_bit_cast(h2_t, hq.x);
                h2_t p1 = __builtin_bit_cast(h2_t, hq.y);
                h2_t p2 = __builtin_bit_cast(h2_t, hq.z);
                h2_t p3 = __builtin_bit_cast(h2_t, hq.w);
                a0 = FDOT2(p0, w2[0][4 * k + 0], a0);
                a1 = FDOT2(p0, w2[1][4 * k + 0], a1);
                a2 = FDOT2(p0, w2[2][4 * k + 0], a2);
                a3 = FDOT2(p0, w2[3][4 * k + 0], a3);
                a0 = FDOT2(p1, w2[0][4 * k + 1], a0);
                a1 = FDOT2(p1, w2[1][4 * k + 1], a1);
                a2 = FDOT2(p1, w2[2][4 * k + 1], a2);
                a3 = FDOT2(p1, w2[3][4 * k + 1], a3);
                a0 = FDOT2(p2, w2[0][4 * k + 2], a0);
                a1 = FDOT2(p2, w2[1][4 * k + 2], a1);
                a2 = FDOT2(p2, w2[2][4 * k + 2], a2);
                a3 = FDOT2(p2, w2[3][4 * k + 2], a3);
                a0 = FDOT2(p3, w2[0][4 * k + 3], a0);
                a1 = FDOT2(p3, w2[1][4 * k + 3], a1);
                a2 = FDOT2(p3, w2[2][4 * k + 3], a2);
                a3 = FDOT2(p3, w2[3][4 * k + 3], a3);
            }
            float f  = sigf(a0);
            float ii = sigf(a1);
            float gg = tanhf_(a2);
            float oo = sigf(a3);
            c = fmaf(f, c, ii * gg);
            float h = oo * tanhf_(c);

            int t = dir ? (T_LEN - 1 - (s0 + q)) : (s0 + q);
            hout[(size_t)t * 128] = h;
            h16[u] = (_Float16)h;            // same-wave RAW, no barrier
        }
        #pragma unroll
        for (int q = 0; q < 4; ++q) zc[q] = zn[q];
    }
}

// ---------------- LSTM layer 2: unit-per-lane, both dirs in ONE wave ----------------
// Block = one b, 64 threads: lanes 0-31 fwd units, 32-63 bwd units.
__global__ __launch_bounds__(64, 1) void lstm2_kernel(
    const float* __restrict__ Z2,
    const float* __restrict__ w2f, const float* __restrict__ w2b,
    float* __restrict__ H2)
{
    const int b   = blockIdx.x;
    const int l   = threadIdx.x;
    const int dir = l >> 5;
    const int u   = l & 31;
    const float* __restrict__ W = dir ? w2b : w2f;

    h2_t w2[4][16];
    #pragma unroll
    for (int g = 0; g < 4; ++g)
        #pragma unroll
        for (int r = 0; r < 16; ++r) {
            float wa = W[(128 + 2 * r) * 128 + g * 32 + u];
            float wb = W[(129 + 2 * r) * 128 + g * 32 + u];
            h2_t p; p[0] = (_Float16)wa; p[1] = (_Float16)wb;
            w2[g][r] = p;
        }

    __shared__ __align__(16) _Float16 h16[2][32];
    h16[dir][u] = (_Float16)0.0f;            // same-wave, all 64 entries covered

    float c = 0.0f, h = 0.0f;

    const float* __restrict__ zrow =
        Z2 + ((size_t)(dir * 64 + b) * 512) * 128 + u * 4;
    const uint4* __restrict__ hb = (const uint4*)h16[dir];

    float4 zc[4], zn[4];
    #pragma unroll
    for (int q = 0; q < 4; ++q) {
        int t = dir ? (T_LEN - 1 - q) : q;
        zc[q] = *(const float4*)&zrow[(size_t)t * 128];
    }

    for (int s0 = 0; s0 < T_LEN; s0 += 4) {
        #pragma unroll
        for (int q = 0; q < 4; ++q) {
            int sp = s0 + 4 + q; if (sp > T_LEN - 1) sp = T_LEN - 1;
            int t = dir ? (T_LEN - 1 - sp) : sp;
            zn[q] = *(const float4*)&zrow[(size_t)t * 128];
        }
        #pragma unroll
        for (int q = 0; q < 4; ++q) {
            float a0 = zc[q].x, a1 = zc[q].y, a2 = zc[q].z, a3 = zc[q].w;
            #pragma unroll
            for (int k = 0; k < 4; ++k) {
                uint4 hq = hb[k];
                h2_t p0 = __builtin_bit_cast(h2_t, hq.x);
                h2_t p1 = __builtin_bit_cast(h2_t, hq.y);
                h2_t p2 = __builtin_bit_cast(h2_t, hq.z);
                h2_t p3 = __builtin_bit_cast(h2_t, hq.w);
                a0 = FDOT2(p0, w2[0][4 * k + 0], a0);
                a1 = FDOT2(p0, w2[1][4 * k + 0], a1);
                a2 = FDOT2(p0, w2[2][4 * k + 0], a2);
                a3 = FDOT2(p0, w2[3][4 * k + 0], a3);
                a0 = FDOT2(p1, w2[0][4 * k + 1], a0);
                a1 = FDOT2(p1, w2[1][4 * k + 1], a1);
                a2 = FDOT2(p1, w2[2][4 * k + 1], a2);
                a3 = FDOT2(p1, w2[3][4 * k + 1], a3);
                a0 = FDOT2(p2, w2[0][4 * k + 2], a0);
                a1 = FDOT2(p2, w2[1][4 * k + 2], a1);
                a2 = FDOT2(p2, w2[2][4 * k + 2], a2);
                a3 = FDOT2(p2, w2[3][4 * k + 2], a3);
                a0 = FDOT2(p3, w2[0][4 * k + 3], a0);
                a1 = FDOT2(p3, w2[1][4 * k + 3], a1);
                a2 = FDOT2(p3, w2[2][4 * k + 3], a2);
                a3 = FDOT2(p3, w2[3][4 * k + 3], a3);
            }
            float f  = sigf(a0);
            float ii = sigf(a1);
            float gg = tanhf_(a2);
            float oo = sigf(a3);
            c = fmaf(f, c, ii * gg);
            h = oo * tanhf_(c);
            h16[dir][u] = (_Float16)h;       // same-wave RAW
        }
        #pragma unroll
        for (int q = 0; q < 4; ++q) { zc[q] = zn[q]; }
    }
    H2[b * 64 + dir * 32 + u] = h;
}

// ---------------- Dense head ----------------
__global__ __launch_bounds__(256) void head_kernel(
    const float* __restrict__ H2,
    const float* __restrict__ wd, const float* __restrict__ bd,
    const float* __restrict__ wo, const float* __restrict__ bo,
    float* __restrict__ out)
{
    const int tid = threadIdx.x;
    const int b = tid >> 2, qd = tid & 3;

    float hv[64];
    #pragma unroll
    for (int v = 0; v < 64; ++v) hv[v] = H2[b * 64 + v];

    float part = 0.0f;
    #pragma unroll
    for (int iq = 0; iq < 8; ++iq) {
        int i = qd * 8 + iq;
        float a = bd[i];
        #pragma unroll
        for (int v = 0; v < 64; ++v)
            a = fmaf(hv[v], wd[v * 32 + i], a);
        a = fmaxf(a, 0.0f);
        part = fmaf(a, wo[i], part);
    }

    __shared__ float ps[256];
    ps[tid] = part;
    __syncthreads();
    if (qd == 0) {
        float s = ps[tid] + ps[tid + 1] + ps[tid + 2] + ps[tid + 3];
        out[b] = sigf(s + bo[0]);
    }
}

extern "C" void kernel_launch(void* const* d_in, const int* in_sizes, int n_in,
                              void* d_out, int out_size, void* d_ws, size_t ws_size,
                              hipStream_t stream)
{
    const int*   tok = (const int*)  d_in[0];
    const float* emb = (const float*)d_in[1];
    const float* w1f = (const float*)d_in[2];
    const float* b1f = (const float*)d_in[3];
    const float* w1b = (const float*)d_in[4];
    const float* b1b = (const float*)d_in[5];
    const float* w2f = (const float*)d_in[6];
    const float* b2f = (const float*)d_in[7];
    const float* w2b = (const float*)d_in[8];
    const float* b2b = (const float*)d_in[9];
    const float* wd  = (const float*)d_in[10];
    const float* bd  = (const float*)d_in[11];
    const float* wo  = (const float*)d_in[12];
    const float* bo  = (const float*)d_in[13];
    float* out = (float*)d_out;

    // Workspace (fp32):
    //   Z1: [2*64][512][256] (67.1 MB); H1: [64][512][128] (16.8 MB); H2: 64x64
    //   Z2 aliases Z1 (dead after lstm1): [2*64][512][128]
    float* Z1 = (float*)d_ws;
    float* H1 = Z1 + (size_t)2 * 64 * 512 * 256;
    float* H2 = H1 + (size_t)64 * 512 * 128;
    float* Z2 = Z1;

    gemm1_kernel<<<dim3(512, 8), 256, 0, stream>>>(tok, emb, w1f, b1f, w1b, b1b, Z1);
    lstm1_kernel<<<128, 64, 0, stream>>>(Z1, w1f, w1b, H1);
    gemm2_kernel<<<dim3(512, 4), 256, 0, stream>>>(H1, w2f, b2f, w2b, b2b, Z2);
    lstm2_kernel<<<64, 64, 0, stream>>>(Z2, w2f, w2b, H2);
    head_kernel<<<1, 256, 0, stream>>>(H2, wd, bd, wo, bo, out);
}

// Round 6
// 546.216 us; speedup vs baseline: 1.6082x; 1.2038x over previous
//
#include <hip/hip_runtime.h>

#define T_LEN 512
#define B_SZ  64

typedef _Float16 h2_t __attribute__((ext_vector_type(2)));

#if defined(__has_builtin)
#  if __has_builtin(__builtin_amdgcn_fdot2)
#    define FDOT2(a, b, c) __builtin_amdgcn_fdot2((a), (b), (c), false)
#  endif
#endif
#ifndef FDOT2
__device__ __forceinline__ float fdot2_fb(h2_t a, h2_t b, float c) {
    return fmaf((float)a[0], (float)b[0], fmaf((float)a[1], (float)b[1], c));
}
#  define FDOT2(a, b, c) fdot2_fb((a), (b), (c))
#endif

__device__ __forceinline__ float sigf(float x) {
    return 1.0f / (1.0f + __expf(-x));
}
__device__ __forceinline__ float tanhf_(float x) {
    return 2.0f / (1.0f + __expf(-2.0f * x)) - 1.0f;
}

// Raw barrier: waits LDS ops only (lgkmcnt), leaves global loads in flight
// across the barrier (no vmcnt drain -> z prefetch ring survives).
__device__ __forceinline__ void lds_barrier() {
    asm volatile("s_waitcnt lgkmcnt(0)" ::: "memory");
    __builtin_amdgcn_s_barrier();
    asm volatile("" ::: "memory");
}

// ---------------- GEMM1: Z1 = gather(emb, tok) @ Wx1 + b1 ----------------
// Z1 layout: [dir*64+b][t][256] natural cols (chain-contiguous streaming)
__global__ __launch_bounds__(256) void gemm1_kernel(
    const int* __restrict__ tok, const float* __restrict__ emb,
    const float* __restrict__ w1f, const float* __restrict__ b1f,
    const float* __restrict__ w1b, const float* __restrict__ b1b,
    float* __restrict__ Z1)
{
    const int b     = blockIdx.x >> 3;
    const int t0    = (blockIdx.x & 7) * 64;
    const int dir   = blockIdx.y >> 2;
    const int nbase = (blockIdx.y & 3) * 64;
    const float* __restrict__ W    = dir ? w1b : w1f;
    const float* __restrict__ bias = dir ? b1b : b1f;

    __shared__ float As[64][20];
    __shared__ float Bs[20][64];
    __shared__ int   toks[64];

    const int tid = threadIdx.x;
    if (tid < 64) toks[tid] = tok[b * T_LEN + t0 + tid];
    __syncthreads();

    float acc[4][4] = {};
    const int ty = tid >> 4, tx = tid & 15;

    for (int k0 = 0; k0 < 300; k0 += 20) {
        #pragma unroll
        for (int q = 0; q < 5; ++q) {
            int idx = tid + q * 256;
            int mm = idx / 20, kk = idx - mm * 20;
            As[mm][kk] = emb[(size_t)toks[mm] * 300 + (k0 + kk)];
            int kk2 = idx >> 6, nn = idx & 63;
            Bs[kk2][nn] = W[(k0 + kk2) * 256 + nbase + nn];
        }
        __syncthreads();
        #pragma unroll
        for (int kk = 0; kk < 20; ++kk) {
            float4 bv = *(const float4*)&Bs[kk][tx * 4];
            #pragma unroll
            for (int i = 0; i < 4; ++i) {
                float a = As[ty * 4 + i][kk];
                acc[i][0] = fmaf(a, bv.x, acc[i][0]);
                acc[i][1] = fmaf(a, bv.y, acc[i][1]);
                acc[i][2] = fmaf(a, bv.z, acc[i][2]);
                acc[i][3] = fmaf(a, bv.w, acc[i][3]);
            }
        }
        __syncthreads();
    }

    const float4 bvad = *(const float4*)&bias[nbase + tx * 4];
    const size_t rbase = (size_t)dir * 32768 + (size_t)b * 512 + t0;
    #pragma unroll
    for (int i = 0; i < 4; ++i) {
        float4 o;
        o.x = acc[i][0] + bvad.x;
        o.y = acc[i][1] + bvad.y;
        o.z = acc[i][2] + bvad.z;
        o.w = acc[i][3] + bvad.w;
        *(float4*)&Z1[(rbase + ty * 4 + i) * 256 + nbase + tx * 4] = o;
    }
}

// ---------------- GEMM2: Z2 = H1 @ Wx2 + b2 ----------------
// H1: [b][t][128] (fwd64|bwd64).  Z2: [dir*64+b][t][128] natural cols
__global__ __launch_bounds__(256) void gemm2_kernel(
    const float* __restrict__ H1,
    const float* __restrict__ w2f, const float* __restrict__ b2f,
    const float* __restrict__ w2b, const float* __restrict__ b2b,
    float* __restrict__ Z2)
{
    const int row0  = blockIdx.x * 64;          // rows r = b*512 + t
    const int dir   = blockIdx.y >> 1;
    const int nbase = (blockIdx.y & 1) * 64;
    const float* __restrict__ W    = dir ? w2b : w2f;
    const float* __restrict__ bias = dir ? b2b : b2f;

    __shared__ float As[64][17];   // +1 pad
    __shared__ float Bs[16][64];

    const int tid = threadIdx.x;
    const int ty = tid >> 4, tx = tid & 15;
    float acc[4][4] = {};

    for (int k0 = 0; k0 < 128; k0 += 16) {
        #pragma unroll
        for (int q = 0; q < 4; ++q) {
            int idx = tid + q * 256;
            int mm = idx >> 4, kk = idx & 15;
            As[mm][kk] = H1[(size_t)(row0 + mm) * 128 + k0 + kk];
            int kk2 = idx >> 6, nn = idx & 63;
            Bs[kk2][nn] = W[(k0 + kk2) * 128 + nbase + nn];
        }
        __syncthreads();
        #pragma unroll
        for (int kk = 0; kk < 16; ++kk) {
            float4 bv = *(const float4*)&Bs[kk][tx * 4];
            #pragma unroll
            for (int i = 0; i < 4; ++i) {
                float a = As[ty * 4 + i][kk];
                acc[i][0] = fmaf(a, bv.x, acc[i][0]);
                acc[i][1] = fmaf(a, bv.y, acc[i][1]);
                acc[i][2] = fmaf(a, bv.z, acc[i][2]);
                acc[i][3] = fmaf(a, bv.w, acc[i][3]);
            }
        }
        __syncthreads();
    }

    const float4 bvad = *(const float4*)&bias[nbase + tx * 4];
    const size_t rbase = (size_t)dir * 32768 + row0;
    #pragma unroll
    for (int i = 0; i < 4; ++i) {
        float4 o;
        o.x = acc[i][0] + bvad.x;
        o.y = acc[i][1] + bvad.y;
        o.z = acc[i][2] + bvad.z;
        o.w = acc[i][3] + bvad.w;
        *(float4*)&Z2[(rbase + ty * 4 + i) * 128 + nbase + tx * 4] = o;
    }
}

// ---------------- LSTM layer 1: 4 waves per chain, 1 gate-column per lane ----
// Block = (b,dir). Wave w owns units 16w..16w+15; lane l: unit u=w*16+(l&15),
// gate g=(l>>4)&3, column col=g*64+u. Weights: 32 VGPRs/lane. Gate exchange:
// 3 intra-wave shuffles. h (64 f16) crosses waves via double-buffered LDS with
// raw lgkm-only barrier (z prefetch ring stays in flight). c,h redundant/lane.
__global__ __launch_bounds__(256, 1) void lstm1_kernel(
    const float* __restrict__ Z1,
    const float* __restrict__ w1f, const float* __restrict__ w1b,
    float* __restrict__ H1)
{
    const int b   = blockIdx.x & 63;
    const int dir = blockIdx.x >> 6;
    const int tid = threadIdx.x;
    const int w   = tid >> 6;
    const int l   = tid & 63;
    const int ul  = l & 15;
    const int g   = (l >> 4) & 3;
    const int u   = w * 16 + ul;
    const int col = g * 64 + u;
    const float* __restrict__ W = dir ? w1b : w1f;

    // Wh column col, f16 pairs over K=64 (rows 300..363)
    h2_t wc[32];
    #pragma unroll
    for (int r = 0; r < 32; ++r) {
        float wa = W[(300 + 2 * r) * 256 + col];
        float wb = W[(301 + 2 * r) * 256 + col];
        h2_t p; p[0] = (_Float16)wa; p[1] = (_Float16)wb;
        wc[r] = p;
    }

    __shared__ __align__(16) _Float16 hbuf[2][64];
    if (g == 0) hbuf[0][u] = (_Float16)0.0f;
    lds_barrier();

    float c = 0.0f;

    const float* __restrict__ zcol =
        Z1 + ((size_t)(dir * 64 + b) * T_LEN) * 256 + col;

    float zr[4];
    #pragma unroll
    for (int q = 0; q < 4; ++q) {
        int t = dir ? (T_LEN - 1 - q) : q;
        zr[q] = zcol[(size_t)t * 256];
    }

    float* __restrict__ hout = H1 + (size_t)b * T_LEN * 128 + dir * 64 + u;

    const bool s0b = (g & 1) != 0, s1b = (g >> 1) != 0;
    const float km  = (g == 2) ? -2.0f : -1.0f;
    const float num = (g == 2) ?  2.0f :  1.0f;
    const float off = (g == 2) ?  1.0f :  0.0f;

    for (int sb = 0; sb < T_LEN; sb += 4) {
        #pragma unroll
        for (int q = 0; q < 4; ++q) {
            const int s = sb + q;
            const uint4* hb = (const uint4*)hbuf[s & 1];
            float a0 = zr[q], a1 = 0.f, a2 = 0.f, a3 = 0.f;
            #pragma unroll
            for (int k = 0; k < 8; ++k) {
                uint4 hq = hb[k];
                h2_t p0 = __builtin_bit_cast(h2_t, hq.x);
                h2_t p1 = __builtin_bit_cast(h2_t, hq.y);
                h2_t p2 = __builtin_bit_cast(h2_t, hq.z);
                h2_t p3 = __builtin_bit_cast(h2_t, hq.w);
                a0 = FDOT2(p0, wc[4 * k + 0], a0);
                a1 = FDOT2(p1, wc[4 * k + 1], a1);
                a2 = FDOT2(p2, wc[4 * k + 2], a2);
                a3 = FDOT2(p3, wc[4 * k + 3], a3);
            }
            float zz = (a0 + a1) + (a2 + a3);

            // refill z ring slot q for step s+4 (stays in flight across barriers)
            {
                int sp = s + 4; if (sp > T_LEN - 1) sp = T_LEN - 1;
                int tp = dir ? (T_LEN - 1 - sp) : sp;
                zr[q] = zcol[(size_t)tp * 256];
            }

            // own gate activation (sig for f,i,o; tanh for g)
            float e = __expf(km * zz);
            float A = num / (1.0f + e) - off;
            // gather the 4 gates of unit u (lanes l, l^16, l^32, l^48)
            float B = __shfl_xor(A, 16);
            float C = __shfl_xor(A, 32);
            float D = __shfl_xor(B, 32);
            float f_ = s1b ? (s0b ? D : C) : (s0b ? B : A);
            float i_ = s1b ? (s0b ? C : D) : (s0b ? A : B);
            float g_ = s1b ? (s0b ? B : A) : (s0b ? D : C);
            float o_ = s1b ? (s0b ? A : B) : (s0b ? C : D);
            c = fmaf(f_, c, i_ * g_);
            float h = o_ * tanhf_(c);
            if (g == 0) {
                int t = dir ? (T_LEN - 1 - s) : s;
                hout[(size_t)t * 128] = h;
                hbuf[(s + 1) & 1][u] = (_Float16)h;
            }
            lds_barrier();
        }
    }
}

// ---------------- LSTM layer 2: same structure, 2 waves per chain ----------
// Block = (b,dir), 128 threads. Lane: unit u=w*16+(l&15) (u<32), gate g,
// column col=g*32+u. K=32 -> 16 fdot2/lane. Final h only.
__global__ __launch_bounds__(128, 1) void lstm2_kernel(
    const float* __restrict__ Z2,
    const float* __restrict__ w2f, const float* __restrict__ w2b,
    float* __restrict__ H2)
{
    const int b   = blockIdx.x & 63;
    const int dir = blockIdx.x >> 6;
    const int tid = threadIdx.x;
    const int w   = tid >> 6;
    const int l   = tid & 63;
    const int ul  = l & 15;
    const int g   = (l >> 4) & 3;
    const int u   = w * 16 + ul;
    const int col = g * 32 + u;
    const float* __restrict__ W = dir ? w2b : w2f;

    h2_t wc[16];
    #pragma unroll
    for (int r = 0; r < 16; ++r) {
        float wa = W[(128 + 2 * r) * 128 + col];
        float wb = W[(129 + 2 * r) * 128 + col];
        h2_t p; p[0] = (_Float16)wa; p[1] = (_Float16)wb;
        wc[r] = p;
    }

    __shared__ __align__(16) _Float16 hbuf[2][32];
    if (g == 0) hbuf[0][u] = (_Float16)0.0f;
    lds_barrier();

    float c = 0.0f, h = 0.0f;

    const float* __restrict__ zcol =
        Z2 + ((size_t)(dir * 64 + b) * T_LEN) * 128 + col;

    float zr[4];
    #pragma unroll
    for (int q = 0; q < 4; ++q) {
        int t = dir ? (T_LEN - 1 - q) : q;
        zr[q] = zcol[(size_t)t * 128];
    }

    const bool s0b = (g & 1) != 0, s1b = (g >> 1) != 0;
    const float km  = (g == 2) ? -2.0f : -1.0f;
    const float num = (g == 2) ?  2.0f :  1.0f;
    const float off = (g == 2) ?  1.0f :  0.0f;

    for (int sb = 0; sb < T_LEN; sb += 4) {
        #pragma unroll
        for (int q = 0; q < 4; ++q) {
            const int s = sb + q;
            const uint4* hb = (const uint4*)hbuf[s & 1];
            float a0 = zr[q], a1 = 0.f, a2 = 0.f, a3 = 0.f;
            #pragma unroll
            for (int k = 0; k < 4; ++k) {
                uint4 hq = hb[k];
                h2_t p0 = __builtin_bit_cast(h2_t, hq.x);
                h2_t p1 = __builtin_bit_cast(h2_t, hq.y);
                h2_t p2 = __builtin_bit_cast(h2_t, hq.z);
                h2_t p3 = __builtin_bit_cast(h2_t, hq.w);
                a0 = FDOT2(p0, wc[4 * k + 0], a0);
                a1 = FDOT2(p1, wc[4 * k + 1], a1);
                a2 = FDOT2(p2, wc[4 * k + 2], a2);
                a3 = FDOT2(p3, wc[4 * k + 3], a3);
            }
            float zz = (a0 + a1) + (a2 + a3);

            {
                int sp = s + 4; if (sp > T_LEN - 1) sp = T_LEN - 1;
                int tp = dir ? (T_LEN - 1 - sp) : sp;
                zr[q] = zcol[(size_t)tp * 128];
            }

            float e = __expf(km * zz);
            float A = num / (1.0f + e) - off;
            float B = __shfl_xor(A, 16);
            float C = __shfl_xor(A, 32);
            float D = __shfl_xor(B, 32);
            float f_ = s1b ? (s0b ? D : C) : (s0b ? B : A);
            float i_ = s1b ? (s0b ? C : D) : (s0b ? A : B);
            float g_ = s1b ? (s0b ? B : A) : (s0b ? D : C);
            float o_ = s1b ? (s0b ? A : B) : (s0b ? C : D);
            c = fmaf(f_, c, i_ * g_);
            h = o_ * tanhf_(c);
            if (g == 0)
                hbuf[(s + 1) & 1][u] = (_Float16)h;
            lds_barrier();
        }
    }
    if (g == 0)
        H2[b * 64 + dir * 32 + u] = h;
}

// ---------------- Dense head ----------------
__global__ __launch_bounds__(256) void head_kernel(
    const float* __restrict__ H2,
    const float* __restrict__ wd, const float* __restrict__ bd,
    const float* __restrict__ wo, const float* __restrict__ bo,
    float* __restrict__ out)
{
    const int tid = threadIdx.x;
    const int b = tid >> 2, qd = tid & 3;

    float hv[64];
    #pragma unroll
    for (int v = 0; v < 64; ++v) hv[v] = H2[b * 64 + v];

    float part = 0.0f;
    #pragma unroll
    for (int iq = 0; iq < 8; ++iq) {
        int i = qd * 8 + iq;
        float a = bd[i];
        #pragma unroll
        for (int v = 0; v < 64; ++v)
            a = fmaf(hv[v], wd[v * 32 + i], a);
        a = fmaxf(a, 0.0f);
        part = fmaf(a, wo[i], part);
    }

    __shared__ float ps[256];
    ps[tid] = part;
    __syncthreads();
    if (qd == 0) {
        float s = ps[tid] + ps[tid + 1] + ps[tid + 2] + ps[tid + 3];
        out[b] = sigf(s + bo[0]);
    }
}

extern "C" void kernel_launch(void* const* d_in, const int* in_sizes, int n_in,
                              void* d_out, int out_size, void* d_ws, size_t ws_size,
                              hipStream_t stream)
{
    const int*   tok = (const int*)  d_in[0];
    const float* emb = (const float*)d_in[1];
    const float* w1f = (const float*)d_in[2];
    const float* b1f = (const float*)d_in[3];
    const float* w1b = (const float*)d_in[4];
    const float* b1b = (const float*)d_in[5];
    const float* w2f = (const float*)d_in[6];
    const float* b2f = (const float*)d_in[7];
    const float* w2b = (const float*)d_in[8];
    const float* b2b = (const float*)d_in[9];
    const float* wd  = (const float*)d_in[10];
    const float* bd  = (const float*)d_in[11];
    const float* wo  = (const float*)d_in[12];
    const float* bo  = (const float*)d_in[13];
    float* out = (float*)d_out;

    // Workspace (fp32):
    //   Z1: [2*64][512][256] (67.1 MB); H1: [64][512][128] (16.8 MB); H2: 64x64
    //   Z2 aliases Z1 (dead after lstm1): [2*64][512][128]
    float* Z1 = (float*)d_ws;
    float* H1 = Z1 + (size_t)2 * 64 * 512 * 256;
    float* H2 = H1 + (size_t)64 * 512 * 128;
    float* Z2 = Z1;

    gemm1_kernel<<<dim3(512, 8), 256, 0, stream>>>(tok, emb, w1f, b1f, w1b, b1b, Z1);
    lstm1_kernel<<<128, 256, 0, stream>>>(Z1, w1f, w1b, H1);
    gemm2_kernel<<<dim3(512, 4), 256, 0, stream>>>(H1, w2f, b2f, w2b, b2b, Z2);
    lstm2_kernel<<<128, 128, 0, stream>>>(Z2, w2f, w2b, H2);
    head_kernel<<<1, 256, 0, stream>>>(H2, wd, bd, wo, bo, out);
}

// Round 7
// 424.675 us; speedup vs baseline: 2.0684x; 1.2862x over previous
//
#include <hip/hip_runtime.h>

#define T_LEN 512
#define B_SZ  64

typedef _Float16 h2_t  __attribute__((ext_vector_type(2)));
typedef _Float16 f16x8 __attribute__((ext_vector_type(8)));
typedef float    f32x4 __attribute__((ext_vector_type(4)));

#if defined(__has_builtin)
#  if __has_builtin(__builtin_amdgcn_fdot2)
#    define FDOT2(a, b, c) __builtin_amdgcn_fdot2((a), (b), (c), false)
#  endif
#endif
#ifndef FDOT2
__device__ __forceinline__ float fdot2_fb(h2_t a, h2_t b, float c) {
    return fmaf((float)a[0], (float)b[0], fmaf((float)a[1], (float)b[1], c));
}
#  define FDOT2(a, b, c) fdot2_fb((a), (b), (c))
#endif

__device__ __forceinline__ float sigf(float x) {
    return 1.0f / (1.0f + __expf(-x));
}
__device__ __forceinline__ float tanhf_(float x) {
    return 2.0f / (1.0f + __expf(-2.0f * x)) - 1.0f;
}
__device__ __forceinline__ unsigned pack2(float x, float y) {
    h2_t p; p[0] = (_Float16)x; p[1] = (_Float16)y;
    return __builtin_bit_cast(unsigned, p);
}

// Raw barrier: waits LDS ops only (lgkmcnt), leaves global loads in flight.
__device__ __forceinline__ void lds_barrier() {
    asm volatile("s_waitcnt lgkmcnt(0)" ::: "memory");
    __builtin_amdgcn_s_barrier();
    asm volatile("" ::: "memory");
}

// ---------------- Prep: Wt1[col 0..511][k 0..319] f16  (col>=256 -> w1b) ----
__global__ __launch_bounds__(64) void prep_w1(
    const float* __restrict__ w1f, const float* __restrict__ w1b,
    _Float16* __restrict__ Wt1)
{
    const int col = blockIdx.x;          // 0..511
    const int t   = threadIdx.x;         // 0..63, octets 0..39 active
    if (t >= 40) return;
    const float* __restrict__ W = (col < 256) ? w1f : w1b;
    const int c = col & 255;
    f16x8 v;
    #pragma unroll
    for (int i = 0; i < 8; ++i) {
        int k = t * 8 + i;
        float x = (k < 300) ? W[(size_t)k * 256 + c] : 0.0f;
        v[i] = (_Float16)x;
    }
    *(f16x8*)(Wt1 + (size_t)col * 320 + t * 8) = v;
}

// ---------------- Prep: Wt2[col 0..255][k 0..127] f16  (col>=128 -> w2b) ----
__global__ __launch_bounds__(64) void prep_w2(
    const float* __restrict__ w2f, const float* __restrict__ w2b,
    _Float16* __restrict__ Wt2)
{
    const int col = blockIdx.x;          // 0..255
    const int t   = threadIdx.x;         // octets 0..15 active
    if (t >= 16) return;
    const float* __restrict__ W = (col < 128) ? w2f : w2b;
    const int c = col & 127;
    f16x8 v;
    #pragma unroll
    for (int i = 0; i < 8; ++i) {
        int k = t * 8 + i;
        v[i] = (_Float16)W[(size_t)k * 128 + c];
    }
    *(f16x8*)(Wt2 + (size_t)col * 128 + t * 8) = v;
}

// ---------------- GEMM1 (MFMA f16): Z1 = gather(emb,tok) @ Wx1 + b1 ----------
// Block: 64 rows (one b, 64 t) x N=512 (fwd 256 | bwd 256), 4 waves.
// Wave w -> cols [w*128, w*128+128) = 8 n-tiles; 4 m-tiles; K=320 (pad), 10 steps.
// A staged once in LDS f16 [64][328] (656B row stride -> 2-way bank = free).
// B fragments loaded straight from L2-resident Wt1 (16B/lane).
// Z1 layout: [dir*64+b][t][256] natural cols.
__global__ __launch_bounds__(256, 1) void gemm1_kernel(
    const int* __restrict__ tok, const float* __restrict__ emb,
    const _Float16* __restrict__ Wt1,
    const float* __restrict__ b1f, const float* __restrict__ b1b,
    float* __restrict__ Z1)
{
    const int row0 = blockIdx.x * 64;            // flat row = b*512 + t
    const int b    = row0 >> 9;
    const int t0   = row0 & 511;
    const int tid  = threadIdx.x;

    __shared__ __align__(16) _Float16 A_lds[64][328];

    // ---- stage A (emb gather, fp32 -> f16, zero-pad k>=300) ----
    {
        const int row = tid >> 2, q = tid & 3;
        const int tk = tok[b * T_LEN + t0 + row];
        const float* __restrict__ src = emb + (size_t)tk * 300 + q * 80;
        #pragma unroll
        for (int i = 0; i < 20; ++i) {
            float4 v;
            if (q == 3 && i >= 15) v = make_float4(0.f, 0.f, 0.f, 0.f);
            else                   v = *(const float4*)(src + i * 4);
            uint2 u; u.x = pack2(v.x, v.y); u.y = pack2(v.z, v.w);
            *(uint2*)&A_lds[row][q * 80 + i * 4] = u;
        }
    }
    __syncthreads();

    const int l   = tid & 63;
    const int w   = tid >> 6;
    const int wN0 = w * 128;
    const int lr  = l & 15;
    const int lk8 = (l >> 4) * 8;

    f32x4 acc[4][8] = {};

    #pragma unroll 2
    for (int ks = 0; ks < 10; ++ks) {
        const int k0 = ks * 32;
        f16x8 af[4];
        #pragma unroll
        for (int m = 0; m < 4; ++m)
            af[m] = *(const f16x8*)&A_lds[m * 16 + lr][k0 + lk8];
        f16x8 bf[8];
        #pragma unroll
        for (int n = 0; n < 8; ++n)
            bf[n] = *(const f16x8*)(Wt1 + (size_t)(wN0 + n * 16 + lr) * 320 + k0 + lk8);
        #pragma unroll
        for (int m = 0; m < 4; ++m)
            #pragma unroll
            for (int n = 0; n < 8; ++n)
                acc[m][n] = __builtin_amdgcn_mfma_f32_16x16x32_f16(af[m], bf[n], acc[m][n], 0, 0, 0);
    }

    // ---- epilogue: bias + store (C/D: col=lane&15, row=(lane>>4)*4+r) ----
    const int dir = wN0 >> 8;
    const int rq  = (l >> 4) * 4;
    #pragma unroll
    for (int n = 0; n < 8; ++n) {
        const int colr = (wN0 + n * 16 + lr) & 255;
        const float bv = dir ? b1b[colr] : b1f[colr];
        #pragma unroll
        for (int m = 0; m < 4; ++m) {
            const size_t rb = (size_t)dir * 32768 + row0 + m * 16 + rq;
            #pragma unroll
            for (int r = 0; r < 4; ++r)
                Z1[(rb + r) * 256 + colr] = acc[m][n][r] + bv;
        }
    }
}

// ---------------- GEMM2 (MFMA f16): Z2 = H1 @ Wx2 + b2 ----------------
// Block: 64 rows x N=256 (fwd 128 | bwd 128), 4 waves; wave -> 4 n-tiles.
// K=128, 4 steps. H1: [b][t][128]. Z2: [dir*64+b][t][128].
__global__ __launch_bounds__(256, 1) void gemm2_kernel(
    const float* __restrict__ H1,
    const _Float16* __restrict__ Wt2,
    const float* __restrict__ b2f, const float* __restrict__ b2b,
    float* __restrict__ Z2)
{
    const int row0 = blockIdx.x * 64;
    const int tid  = threadIdx.x;

    __shared__ __align__(16) _Float16 A_lds[64][136];

    {
        const int row = tid >> 2, q = tid & 3;
        const float* __restrict__ src = H1 + (size_t)(row0 + row) * 128 + q * 32;
        #pragma unroll
        for (int i = 0; i < 8; ++i) {
            float4 v = *(const float4*)(src + i * 4);
            uint2 u; u.x = pack2(v.x, v.y); u.y = pack2(v.z, v.w);
            *(uint2*)&A_lds[row][q * 32 + i * 4] = u;
        }
    }
    __syncthreads();

    const int l   = tid & 63;
    const int w   = tid >> 6;
    const int wN0 = w * 64;
    const int lr  = l & 15;
    const int lk8 = (l >> 4) * 8;

    f32x4 acc[4][4] = {};

    #pragma unroll
    for (int ks = 0; ks < 4; ++ks) {
        const int k0 = ks * 32;
        f16x8 af[4];
        #pragma unroll
        for (int m = 0; m < 4; ++m)
            af[m] = *(const f16x8*)&A_lds[m * 16 + lr][k0 + lk8];
        f16x8 bf[4];
        #pragma unroll
        for (int n = 0; n < 4; ++n)
            bf[n] = *(const f16x8*)(Wt2 + (size_t)(wN0 + n * 16 + lr) * 128 + k0 + lk8);
        #pragma unroll
        for (int m = 0; m < 4; ++m)
            #pragma unroll
            for (int n = 0; n < 4; ++n)
                acc[m][n] = __builtin_amdgcn_mfma_f32_16x16x32_f16(af[m], bf[n], acc[m][n], 0, 0, 0);
    }

    const int dir = wN0 >> 7;
    const int rq  = (l >> 4) * 4;
    #pragma unroll
    for (int n = 0; n < 4; ++n) {
        const int colr = (wN0 + n * 16 + lr) & 127;
        const float bv = dir ? b2b[colr] : b2f[colr];
        #pragma unroll
        for (int m = 0; m < 4; ++m) {
            const size_t rb = (size_t)dir * 32768 + row0 + m * 16 + rq;
            #pragma unroll
            for (int r = 0; r < 4; ++r)
                Z2[(rb + r) * 128 + colr] = acc[m][n][r] + bv;
        }
    }
}

// ---------------- LSTM layer 1: 4 waves per chain, 1 gate-column per lane ----
__global__ __launch_bounds__(256, 1) void lstm1_kernel(
    const float* __restrict__ Z1,
    const float* __restrict__ w1f, const float* __restrict__ w1b,
    float* __restrict__ H1)
{
    const int b   = blockIdx.x & 63;
    const int dir = blockIdx.x >> 6;
    const int tid = threadIdx.x;
    const int w   = tid >> 6;
    const int l   = tid & 63;
    const int ul  = l & 15;
    const int g   = (l >> 4) & 3;
    const int u   = w * 16 + ul;
    const int col = g * 64 + u;
    const float* __restrict__ W = dir ? w1b : w1f;

    h2_t wc[32];
    #pragma unroll
    for (int r = 0; r < 32; ++r) {
        float wa = W[(300 + 2 * r) * 256 + col];
        float wb = W[(301 + 2 * r) * 256 + col];
        h2_t p; p[0] = (_Float16)wa; p[1] = (_Float16)wb;
        wc[r] = p;
    }

    __shared__ __align__(16) _Float16 hbuf[2][64];
    if (g == 0) hbuf[0][u] = (_Float16)0.0f;
    lds_barrier();

    float c = 0.0f;

    const float* __restrict__ zcol =
        Z1 + ((size_t)(dir * 64 + b) * T_LEN) * 256 + col;

    float zr[4];
    #pragma unroll
    for (int q = 0; q < 4; ++q) {
        int t = dir ? (T_LEN - 1 - q) : q;
        zr[q] = zcol[(size_t)t * 256];
    }

    float* __restrict__ hout = H1 + (size_t)b * T_LEN * 128 + dir * 64 + u;

    const bool s0b = (g & 1) != 0, s1b = (g >> 1) != 0;
    const float km  = (g == 2) ? -2.0f : -1.0f;
    const float num = (g == 2) ?  2.0f :  1.0f;
    const float off = (g == 2) ?  1.0f :  0.0f;

    for (int sb = 0; sb < T_LEN; sb += 4) {
        #pragma unroll
        for (int q = 0; q < 4; ++q) {
            const int s = sb + q;
            const uint4* hb = (const uint4*)hbuf[s & 1];
            float a0 = zr[q], a1 = 0.f, a2 = 0.f, a3 = 0.f;
            #pragma unroll
            for (int k = 0; k < 8; ++k) {
                uint4 hq = hb[k];
                h2_t p0 = __builtin_bit_cast(h2_t, hq.x);
                h2_t p1 = __builtin_bit_cast(h2_t, hq.y);
                h2_t p2 = __builtin_bit_cast(h2_t, hq.z);
                h2_t p3 = __builtin_bit_cast(h2_t, hq.w);
                a0 = FDOT2(p0, wc[4 * k + 0], a0);
                a1 = FDOT2(p1, wc[4 * k + 1], a1);
                a2 = FDOT2(p2, wc[4 * k + 2], a2);
                a3 = FDOT2(p3, wc[4 * k + 3], a3);
            }
            float zz = (a0 + a1) + (a2 + a3);

            {
                int sp = s + 4; if (sp > T_LEN - 1) sp = T_LEN - 1;
                int tp = dir ? (T_LEN - 1 - sp) : sp;
                zr[q] = zcol[(size_t)tp * 256];
            }

            float e = __expf(km * zz);
            float A = num / (1.0f + e) - off;
            float B = __shfl_xor(A, 16);
            float C = __shfl_xor(A, 32);
            float D = __shfl_xor(B, 32);
            float f_ = s1b ? (s0b ? D : C) : (s0b ? B : A);
            float i_ = s1b ? (s0b ? C : D) : (s0b ? A : B);
            float g_ = s1b ? (s0b ? B : A) : (s0b ? D : C);
            float o_ = s1b ? (s0b ? A : B) : (s0b ? C : D);
            c = fmaf(f_, c, i_ * g_);
            float h = o_ * tanhf_(c);
            if (g == 0) {
                int t = dir ? (T_LEN - 1 - s) : s;
                hout[(size_t)t * 128] = h;
                hbuf[(s + 1) & 1][u] = (_Float16)h;
            }
            lds_barrier();
        }
    }
}

// ---------------- LSTM layer 2: same structure, 2 waves per chain ----------
__global__ __launch_bounds__(128, 1) void lstm2_kernel(
    const float* __restrict__ Z2,
    const float* __restrict__ w2f, const float* __restrict__ w2b,
    float* __restrict__ H2)
{
    const int b   = blockIdx.x & 63;
    const int dir = blockIdx.x >> 6;
    const int tid = threadIdx.x;
    const int w   = tid >> 6;
    const int l   = tid & 63;
    const int ul  = l & 15;
    const int g   = (l >> 4) & 3;
    const int u   = w * 16 + ul;
    const int col = g * 32 + u;
    const float* __restrict__ W = dir ? w2b : w2f;

    h2_t wc[16];
    #pragma unroll
    for (int r = 0; r < 16; ++r) {
        float wa = W[(128 + 2 * r) * 128 + col];
        float wb = W[(129 + 2 * r) * 128 + col];
        h2_t p; p[0] = (_Float16)wa; p[1] = (_Float16)wb;
        wc[r] = p;
    }

    __shared__ __align__(16) _Float16 hbuf[2][32];
    if (g == 0) hbuf[0][u] = (_Float16)0.0f;
    lds_barrier();

    float c = 0.0f, h = 0.0f;

    const float* __restrict__ zcol =
        Z2 + ((size_t)(dir * 64 + b) * T_LEN) * 128 + col;

    float zr[4];
    #pragma unroll
    for (int q = 0; q < 4; ++q) {
        int t = dir ? (T_LEN - 1 - q) : q;
        zr[q] = zcol[(size_t)t * 128];
    }

    const bool s0b = (g & 1) != 0, s1b = (g >> 1) != 0;
    const float km  = (g == 2) ? -2.0f : -1.0f;
    const float num = (g == 2) ?  2.0f :  1.0f;
    const float off = (g == 2) ?  1.0f :  0.0f;

    for (int sb = 0; sb < T_LEN; sb += 4) {
        #pragma unroll
        for (int q = 0; q < 4; ++q) {
            const int s = sb + q;
            const uint4* hb = (const uint4*)hbuf[s & 1];
            float a0 = zr[q], a1 = 0.f, a2 = 0.f, a3 = 0.f;
            #pragma unroll
            for (int k = 0; k < 4; ++k) {
                uint4 hq = hb[k];
                h2_t p0 = __builtin_bit_cast(h2_t, hq.x);
                h2_t p1 = __builtin_bit_cast(h2_t, hq.y);
                h2_t p2 = __builtin_bit_cast(h2_t, hq.z);
                h2_t p3 = __builtin_bit_cast(h2_t, hq.w);
                a0 = FDOT2(p0, wc[4 * k + 0], a0);
                a1 = FDOT2(p1, wc[4 * k + 1], a1);
                a2 = FDOT2(p2, wc[4 * k + 2], a2);
                a3 = FDOT2(p3, wc[4 * k + 3], a3);
            }
            float zz = (a0 + a1) + (a2 + a3);

            {
                int sp = s + 4; if (sp > T_LEN - 1) sp = T_LEN - 1;
                int tp = dir ? (T_LEN - 1 - sp) : sp;
                zr[q] = zcol[(size_t)tp * 128];
            }

            float e = __expf(km * zz);
            float A = num / (1.0f + e) - off;
            float B = __shfl_xor(A, 16);
            float C = __shfl_xor(A, 32);
            float D = __shfl_xor(B, 32);
            float f_ = s1b ? (s0b ? D : C) : (s0b ? B : A);
            float i_ = s1b ? (s0b ? C : D) : (s0b ? A : B);
            float g_ = s1b ? (s0b ? B : A) : (s0b ? D : C);
            float o_ = s1b ? (s0b ? A : B) : (s0b ? C : D);
            c = fmaf(f_, c, i_ * g_);
            h = o_ * tanhf_(c);
            if (g == 0)
                hbuf[(s + 1) & 1][u] = (_Float16)h;
            lds_barrier();
        }
    }
    if (g == 0)
        H2[b * 64 + dir * 32 + u] = h;
}

// ---------------- Dense head ----------------
__global__ __launch_bounds__(256) void head_kernel(
    const float* __restrict__ H2,
    const float* __restrict__ wd, const float* __restrict__ bd,
    const float* __restrict__ wo, const float* __restrict__ bo,
    float* __restrict__ out)
{
    const int tid = threadIdx.x;
    const int b = tid >> 2, qd = tid & 3;

    float hv[64];
    #pragma unroll
    for (int v = 0; v < 64; ++v) hv[v] = H2[b * 64 + v];

    float part = 0.0f;
    #pragma unroll
    for (int iq = 0; iq < 8; ++iq) {
        int i = qd * 8 + iq;
        float a = bd[i];
        #pragma unroll
        for (int v = 0; v < 64; ++v)
            a = fmaf(hv[v], wd[v * 32 + i], a);
        a = fmaxf(a, 0.0f);
        part = fmaf(a, wo[i], part);
    }

    __shared__ float ps[256];
    ps[tid] = part;
    __syncthreads();
    if (qd == 0) {
        float s = ps[tid] + ps[tid + 1] + ps[tid + 2] + ps[tid + 3];
        out[b] = sigf(s + bo[0]);
    }
}

extern "C" void kernel_launch(void* const* d_in, const int* in_sizes, int n_in,
                              void* d_out, int out_size, void* d_ws, size_t ws_size,
                              hipStream_t stream)
{
    const int*   tok = (const int*)  d_in[0];
    const float* emb = (const float*)d_in[1];
    const float* w1f = (const float*)d_in[2];
    const float* b1f = (const float*)d_in[3];
    const float* w1b = (const float*)d_in[4];
    const float* b1b = (const float*)d_in[5];
    const float* w2f = (const float*)d_in[6];
    const float* b2f = (const float*)d_in[7];
    const float* w2b = (const float*)d_in[8];
    const float* b2b = (const float*)d_in[9];
    const float* wd  = (const float*)d_in[10];
    const float* bd  = (const float*)d_in[11];
    const float* wo  = (const float*)d_in[12];
    const float* bo  = (const float*)d_in[13];
    float* out = (float*)d_out;

    // Workspace:
    //   Z1 : [2*64][512][256] fp32 (67.1 MB)
    //   H1 : [64][512][128]  fp32 (16.8 MB)
    //   H2 : 64x64 fp32
    //   Wt1: [512][320] f16 (0.33 MB)   x-part of W1, transposed+padded
    //   Wt2: [256][128] f16 (65 KB)     x-part of W2, transposed
    //   Z2 aliases Z1 (dead after lstm1)
    float* Z1 = (float*)d_ws;
    float* H1 = Z1 + (size_t)2 * 64 * 512 * 256;
    float* H2 = H1 + (size_t)64 * 512 * 128;
    _Float16* Wt1 = (_Float16*)(H2 + 4096);
    _Float16* Wt2 = Wt1 + (size_t)512 * 320;
    float* Z2 = Z1;

    prep_w1<<<512, 64, 0, stream>>>(w1f, w1b, Wt1);
    prep_w2<<<256, 64, 0, stream>>>(w2f, w2b, Wt2);
    gemm1_kernel<<<512, 256, 0, stream>>>(tok, emb, Wt1, b1f, b1b, Z1);
    lstm1_kernel<<<128, 256, 0, stream>>>(Z1, w1f, w1b, H1);
    gemm2_kernel<<<512, 256, 0, stream>>>(H1, Wt2, b2f, b2b, Z2);
    lstm2_kernel<<<128, 128, 0, stream>>>(Z2, w2f, w2b, H2);
    head_kernel<<<1, 256, 0, stream>>>(H2, wd, bd, wo, bo, out);
}